// Round 1
// baseline (801.753 us; speedup 1.0000x reference)
//
#include <hip/hip_runtime.h>

#define NB 32
#define IN_DIM 256
#define NT 512
#define NL 512
#define NCONN 256
#define BT 8
#define LN_EPS 1e-3f

// ---------------------------------------------------------------------------
// Kernel 1: z = LN(cos(xt @ Wf + bf)) for 8 consecutive t-rows per block.
// ---------------------------------------------------------------------------
__global__ __launch_bounds__(512) void k1_fourier_ln(
    const float* __restrict__ x, const float* __restrict__ Wf,
    const float* __restrict__ bf, const float* __restrict__ gamma,
    const float* __restrict__ beta, float* __restrict__ z)
{
    __shared__ float xs[IN_DIM][BT];      // transposed: xs[k][r]
    __shared__ float redS[BT][8], redQ[BT][8];
    __shared__ float redM[BT], redR[BT];

    const int blk = blockIdx.x;
    const int b  = blk / (NT / BT);
    const int t0 = (blk % (NT / BT)) * BT;
    const int tid = threadIdx.x;

    // load x[b, k, t0+r] -> xs[k][r]; r-fastest => conflict-free LDS writes
    for (int i = tid; i < IN_DIM * BT; i += 512) {
        const int r = i & (BT - 1), k = i >> 3;
        xs[k][r] = x[((size_t)b * IN_DIM + k) * NT + t0 + r];
    }
    __syncthreads();

    const int l = tid;
    float acc[BT];
#pragma unroll
    for (int r = 0; r < BT; r++) acc[r] = 0.f;

    const float* wp = Wf + l;
    for (int k = 0; k < IN_DIM; k++) {
        const float w = wp[k * NL];
        const float4 a0 = *(const float4*)&xs[k][0];
        const float4 a1 = *(const float4*)&xs[k][4];
        acc[0] += a0.x * w; acc[1] += a0.y * w; acc[2] += a0.z * w; acc[3] += a0.w * w;
        acc[4] += a1.x * w; acc[5] += a1.y * w; acc[6] += a1.z * w; acc[7] += a1.w * w;
    }

    const float bfl = bf[l];
    float p[BT], s1[BT], s2[BT];
#pragma unroll
    for (int r = 0; r < BT; r++) {
        p[r] = __cosf(acc[r] + bfl);
        s1[r] = p[r];
        s2[r] = p[r] * p[r];
    }
#pragma unroll
    for (int off = 32; off >= 1; off >>= 1) {
#pragma unroll
        for (int r = 0; r < BT; r++) {
            s1[r] += __shfl_xor(s1[r], off);
            s2[r] += __shfl_xor(s2[r], off);
        }
    }
    const int wave = tid >> 6, lane = tid & 63;
    if (lane == 0) {
#pragma unroll
        for (int r = 0; r < BT; r++) { redS[r][wave] = s1[r]; redQ[r][wave] = s2[r]; }
    }
    __syncthreads();
    if (tid < BT) {
        float a = 0.f, q = 0.f;
#pragma unroll
        for (int w = 0; w < 8; w++) { a += redS[tid][w]; q += redQ[tid][w]; }
        const float mu = a * (1.0f / NL);
        const float var = q * (1.0f / NL) - mu * mu;
        redM[tid] = mu;
        redR[tid] = rsqrtf(var + LN_EPS);
    }
    __syncthreads();

    const float g = gamma[l], be = beta[l];
#pragma unroll
    for (int r = 0; r < BT; r++) {
        const float zv = g * (p[r] - redM[r]) * redR[r] + be;
        z[((size_t)(b * NT) + t0 + r) * NL + l] = zv;
    }
}

// ---------------------------------------------------------------------------
// Kernel 2: gates. For 8 rows per block:
//   i = sigmoid(z@Wi + z_prev@Ri + bi), f = sigmoid(z@Wg + z_prev@Rg + bg)
//   u = conn@Wc + bc; store f and i*u.
// ---------------------------------------------------------------------------
__global__ __launch_bounds__(512) void k2_gates(
    const float* __restrict__ z, const float* __restrict__ conn,
    const float* __restrict__ Wi, const float* __restrict__ Ri, const float* __restrict__ bi,
    const float* __restrict__ Wg, const float* __restrict__ Rg, const float* __restrict__ bg,
    const float* __restrict__ Wc, const float* __restrict__ bc,
    const float* __restrict__ init_h,
    float* __restrict__ fbuf, float* __restrict__ iubuf)
{
    __shared__ float zs[NL][BT];      // current rows, transposed [k][r]
    __shared__ float zp[NL][BT];      // previous rows
    __shared__ float cn[NCONN][BT];   // connectivity rows

    const int blk = blockIdx.x;
    const int b  = blk / (NT / BT);
    const int t0 = (blk % (NT / BT)) * BT;
    const int tid = threadIdx.x;
    const size_t zbase = (size_t)b * NT * NL;

    for (int i = tid; i < NL * BT; i += 512) {
        const int r = i & (BT - 1), k = i >> 3;
        zs[k][r] = z[zbase + (size_t)(t0 + r) * NL + k];
        const int tp = t0 + r - 1;
        zp[k][r] = (tp < 0) ? init_h[k] : z[zbase + (size_t)tp * NL + k];
    }
    for (int i = tid; i < NCONN * BT; i += 512) {
        const int r = i & (BT - 1), k = i >> 3;
        cn[k][r] = conn[((size_t)(b * NT) + t0 + r) * NCONN + k];
    }
    __syncthreads();

    const int l = tid;
    float ai[BT], af[BT], u[BT];
    const float bil = bi[l], bgl = bg[l];
#pragma unroll
    for (int r = 0; r < BT; r++) { ai[r] = bil; af[r] = bgl; u[r] = 0.f; }

    // z @ Wi, z @ Wg
    {
        const float* wi = Wi + l;
        const float* wg = Wg + l;
        for (int k = 0; k < NL; k++) {
            const float a = wi[k * NL];
            const float c = wg[k * NL];
            const float4 z0 = *(const float4*)&zs[k][0];
            const float4 z1 = *(const float4*)&zs[k][4];
            ai[0] += z0.x * a; ai[1] += z0.y * a; ai[2] += z0.z * a; ai[3] += z0.w * a;
            ai[4] += z1.x * a; ai[5] += z1.y * a; ai[6] += z1.z * a; ai[7] += z1.w * a;
            af[0] += z0.x * c; af[1] += z0.y * c; af[2] += z0.z * c; af[3] += z0.w * c;
            af[4] += z1.x * c; af[5] += z1.y * c; af[6] += z1.z * c; af[7] += z1.w * c;
        }
    }
    // z_prev @ Ri, z_prev @ Rg
    {
        const float* ri = Ri + l;
        const float* rg = Rg + l;
        for (int k = 0; k < NL; k++) {
            const float a = ri[k * NL];
            const float c = rg[k * NL];
            const float4 z0 = *(const float4*)&zp[k][0];
            const float4 z1 = *(const float4*)&zp[k][4];
            ai[0] += z0.x * a; ai[1] += z0.y * a; ai[2] += z0.z * a; ai[3] += z0.w * a;
            ai[4] += z1.x * a; ai[5] += z1.y * a; ai[6] += z1.z * a; ai[7] += z1.w * a;
            af[0] += z0.x * c; af[1] += z0.y * c; af[2] += z0.z * c; af[3] += z0.w * c;
            af[4] += z1.x * c; af[5] += z1.y * c; af[6] += z1.z * c; af[7] += z1.w * c;
        }
    }
    // conn @ Wc
    {
        const float* wc = Wc + l;
        for (int k = 0; k < NCONN; k++) {
            const float a = wc[k * NL];
            const float4 c0 = *(const float4*)&cn[k][0];
            const float4 c1 = *(const float4*)&cn[k][4];
            u[0] += c0.x * a; u[1] += c0.y * a; u[2] += c0.z * a; u[3] += c0.w * a;
            u[4] += c1.x * a; u[5] += c1.y * a; u[6] += c1.z * a; u[7] += c1.w * a;
        }
    }

    const float bcl = bc[l];
#pragma unroll
    for (int r = 0; r < BT; r++) {
        const float iv = 1.f / (1.f + __expf(-ai[r]));
        const float fv = 1.f / (1.f + __expf(-af[r]));
        const size_t idx = ((size_t)(b * NT) + t0 + r) * NL + l;
        fbuf[idx]  = fv;
        iubuf[idx] = iv * (u[r] + bcl);
    }
}

// ---------------------------------------------------------------------------
// Kernel 3: sequential scan over T per (b,l); h = sin(z)*c; out[b,l,t].
// ---------------------------------------------------------------------------
__global__ __launch_bounds__(512) void k3_scan(
    const float* __restrict__ z, const float* __restrict__ fbuf,
    const float* __restrict__ iubuf, const float* __restrict__ init_c,
    float* __restrict__ out)
{
    const int b = blockIdx.x;
    const int l = threadIdx.x;
    float c = init_c[l];

    const float* zpt = z     + (size_t)b * NT * NL + l;
    const float* fpt = fbuf  + (size_t)b * NT * NL + l;
    const float* ipt = iubuf + (size_t)b * NT * NL + l;
    float* op = out + ((size_t)b * NL + l) * NT;

    for (int t0 = 0; t0 < NT; t0 += 16) {
        float h[16];
#pragma unroll
        for (int j = 0; j < 16; j++) {
            const size_t off = (size_t)(t0 + j) * NL;
            const float fv = fpt[off];
            const float iv = ipt[off];
            const float zv = zpt[off];
            c = fv * c + iv;
            h[j] = __sinf(zv) * c;
        }
        float4* o4 = (float4*)(op + t0);
        o4[0] = make_float4(h[0],  h[1],  h[2],  h[3]);
        o4[1] = make_float4(h[4],  h[5],  h[6],  h[7]);
        o4[2] = make_float4(h[8],  h[9],  h[10], h[11]);
        o4[3] = make_float4(h[12], h[13], h[14], h[15]);
    }
}

// ---------------------------------------------------------------------------
extern "C" void kernel_launch(void* const* d_in, const int* in_sizes, int n_in,
                              void* d_out, int out_size, void* d_ws, size_t ws_size,
                              hipStream_t stream)
{
    const float* x      = (const float*)d_in[0];
    const float* conn   = (const float*)d_in[1];
    const float* Wf     = (const float*)d_in[2];
    const float* bf     = (const float*)d_in[3];
    const float* gamma  = (const float*)d_in[4];
    const float* beta   = (const float*)d_in[5];
    const float* Wi     = (const float*)d_in[6];
    const float* Ri     = (const float*)d_in[7];
    const float* bi     = (const float*)d_in[8];
    const float* Wg     = (const float*)d_in[9];
    const float* Rg     = (const float*)d_in[10];
    const float* bg     = (const float*)d_in[11];
    const float* Wc     = (const float*)d_in[12];
    const float* bc     = (const float*)d_in[13];
    const float* init_h = (const float*)d_in[14];
    const float* init_c = (const float*)d_in[15];

    float* ws = (float*)d_ws;
    const size_t NBT = (size_t)NB * NT * NL;
    float* zbuf  = ws;
    float* fb    = ws + NBT;
    float* iub   = ws + 2 * NBT;

    const int rows_blocks = NB * NT / BT;   // 2048

    k1_fourier_ln<<<rows_blocks, 512, 0, stream>>>(x, Wf, bf, gamma, beta, zbuf);
    k2_gates<<<rows_blocks, 512, 0, stream>>>(zbuf, conn, Wi, Ri, bi, Wg, Rg, bg,
                                              Wc, bc, init_h, fb, iub);
    k3_scan<<<NB, 512, 0, stream>>>(zbuf, fb, iub, init_c, (float*)d_out);
}

// Round 2
// 320.298 us; speedup vs baseline: 2.5031x; 2.5031x over previous
//
#include <hip/hip_runtime.h>
#include <hip/hip_bf16.h>

#define NB 32
#define IN_DIM 256
#define NT 512
#define NL 512
#define NCONN 256
#define BT 8
#define LN_EPS 1e-3f
#define M_TOT (NB * NT)   // 16384 rows

typedef __attribute__((ext_vector_type(8))) short short8;
typedef __attribute__((ext_vector_type(4))) float f32x4;

__device__ __forceinline__ void async_copy16(void* lds_dst, const void* g_src) {
    __builtin_amdgcn_global_load_lds(
        (const __attribute__((address_space(1))) unsigned int*)g_src,
        (__attribute__((address_space(3))) unsigned int*)lds_dst, 16, 0, 0);
}

// ---------------------------------------------------------------------------
// Kernel 1: z = LN(cos(xt @ Wf + bf)); writes z (f32) and A = [z | z_prev] bf16
// ---------------------------------------------------------------------------
__global__ __launch_bounds__(512) void k1_fourier_ln(
    const float* __restrict__ x, const float* __restrict__ Wf,
    const float* __restrict__ bf, const float* __restrict__ gamma,
    const float* __restrict__ beta, const float* __restrict__ init_h,
    float* __restrict__ zbuf, __hip_bfloat16* __restrict__ abuf)
{
    __shared__ float xs[IN_DIM][BT];
    __shared__ float redS[BT][8], redQ[BT][8];
    __shared__ float redM[BT], redR[BT];

    const int blk = blockIdx.x;
    const int b  = blk / (NT / BT);
    const int t0 = (blk % (NT / BT)) * BT;
    const int tid = threadIdx.x;

    for (int i = tid; i < IN_DIM * BT; i += 512) {
        const int r = i & (BT - 1), k = i >> 3;
        xs[k][r] = x[((size_t)b * IN_DIM + k) * NT + t0 + r];
    }
    __syncthreads();

    const int l = tid;
    float acc[BT];
#pragma unroll
    for (int r = 0; r < BT; r++) acc[r] = 0.f;

    const float* wp = Wf + l;
    for (int k = 0; k < IN_DIM; k++) {
        const float w = wp[k * NL];
        const float4 a0 = *(const float4*)&xs[k][0];
        const float4 a1 = *(const float4*)&xs[k][4];
        acc[0] += a0.x * w; acc[1] += a0.y * w; acc[2] += a0.z * w; acc[3] += a0.w * w;
        acc[4] += a1.x * w; acc[5] += a1.y * w; acc[6] += a1.z * w; acc[7] += a1.w * w;
    }

    const float bfl = bf[l];
    float p[BT], s1[BT], s2[BT];
#pragma unroll
    for (int r = 0; r < BT; r++) {
        p[r] = __cosf(acc[r] + bfl);
        s1[r] = p[r];
        s2[r] = p[r] * p[r];
    }
#pragma unroll
    for (int off = 32; off >= 1; off >>= 1) {
#pragma unroll
        for (int r = 0; r < BT; r++) {
            s1[r] += __shfl_xor(s1[r], off);
            s2[r] += __shfl_xor(s2[r], off);
        }
    }
    const int wave = tid >> 6, lane = tid & 63;
    if (lane == 0) {
#pragma unroll
        for (int r = 0; r < BT; r++) { redS[r][wave] = s1[r]; redQ[r][wave] = s2[r]; }
    }
    __syncthreads();
    if (tid < BT) {
        float a = 0.f, q = 0.f;
#pragma unroll
        for (int w = 0; w < 8; w++) { a += redS[tid][w]; q += redQ[tid][w]; }
        const float mu = a * (1.0f / NL);
        const float var = q * (1.0f / NL) - mu * mu;
        redM[tid] = mu;
        redR[tid] = rsqrtf(var + LN_EPS);
    }
    __syncthreads();

    const float g = gamma[l], be = beta[l];
#pragma unroll
    for (int r = 0; r < BT; r++) {
        const float zv = g * (p[r] - redM[r]) * redR[r] + be;
        const int t = t0 + r;
        const size_t m = (size_t)b * NT + t;
        zbuf[m * NL + l] = zv;
        const __hip_bfloat16 zb = __float2bfloat16(zv);
        abuf[m * 1024 + l] = zb;                       // A[:, 0:512] = z
        if (t < NT - 1) abuf[(m + 1) * 1024 + 512 + l] = zb;  // A[t+1, 512:] = z_t
    }
    if (t0 == 0) abuf[(size_t)b * NT * 1024 + 512 + l] = __float2bfloat16(init_h[l]);
}

// ---------------------------------------------------------------------------
// Weight transpose+convert: dst[n][k_off+k] = bf16(src[k][n]); src is K x N.
// ---------------------------------------------------------------------------
__global__ __launch_bounds__(256) void wconv_transpose(
    const float* __restrict__ src, __hip_bfloat16* __restrict__ dst,
    int K, int N, int lddst, int k_off)
{
    __shared__ float t[64][65];
    const int ntn = N >> 6;
    const int k0 = (blockIdx.x / ntn) << 6;
    const int n0 = (blockIdx.x % ntn) << 6;
    const int tid = threadIdx.x;
    for (int idx = tid; idx < 4096; idx += 256) {
        const int kk = idx >> 6, nn = idx & 63;
        t[kk][nn] = src[(size_t)(k0 + kk) * N + n0 + nn];
    }
    __syncthreads();
    for (int idx = tid; idx < 4096; idx += 256) {
        const int nn = idx >> 6, kk = idx & 63;
        dst[(size_t)(n0 + nn) * lddst + k_off + k0 + kk] = __float2bfloat16(t[kk][nn]);
    }
}

// ---------------------------------------------------------------------------
// conn f32 -> bf16
// ---------------------------------------------------------------------------
__global__ __launch_bounds__(256) void conv_bf16_vec(
    const float* __restrict__ src, __hip_bfloat16* __restrict__ dst, int n)
{
    const int e = (blockIdx.x * 256 + threadIdx.x) * 4;
    if (e < n) {
        const float4 v = *(const float4*)(src + e);
        dst[e + 0] = __float2bfloat16(v.x);
        dst[e + 1] = __float2bfloat16(v.y);
        dst[e + 2] = __float2bfloat16(v.z);
        dst[e + 3] = __float2bfloat16(v.w);
    }
}

// ---------------------------------------------------------------------------
// MFMA GEMM, 128x128 tile, BK=64, 4 waves. A: M x KTOT bf16 row-major.
// B matrices: N x KTOT bf16 (pre-transposed, k-fastest).
// DUAL: acc0 = A@B0^T (gate i), acc1 = A@B1^T (gate g); epilogue:
//   f = sigmoid(acc1+bg) -> out0 ; iu = sigmoid(acc0+bi)*(uio+bc) -> uio.
// !DUAL: out0 = A@B0^T.
// ---------------------------------------------------------------------------
template<int KTOT, bool DUAL>
__global__ __launch_bounds__(256) void gemm_mfma(
    const __hip_bfloat16* __restrict__ A,
    const __hip_bfloat16* __restrict__ B0,
    const __hip_bfloat16* __restrict__ B1,
    const float* __restrict__ bi, const float* __restrict__ bg,
    const float* __restrict__ bc,
    float* __restrict__ out0, float* __restrict__ uio)
{
    __shared__ ushort sA[128 * 64];
    __shared__ ushort sB0[128 * 64];
    __shared__ ushort sB1[DUAL ? 128 * 64 : 16];

    const int tid = threadIdx.x;
    const int wave = tid >> 6, lane = tid & 63;
    const int wr = wave >> 1, wc = wave & 1;
    const int m0 = blockIdx.x * 128;
    const int n0 = blockIdx.y * 128;

    f32x4 acc0[4][4];
    f32x4 acc1[DUAL ? 4 : 1][DUAL ? 4 : 1];
#pragma unroll
    for (int mi = 0; mi < 4; mi++)
#pragma unroll
        for (int ni = 0; ni < 4; ni++) acc0[mi][ni] = f32x4{0.f, 0.f, 0.f, 0.f};
    if constexpr (DUAL) {
#pragma unroll
        for (int mi = 0; mi < 4; mi++)
#pragma unroll
            for (int ni = 0; ni < 4; ni++) acc1[mi][ni] = f32x4{0.f, 0.f, 0.f, 0.f};
    }

    // staging: lane writes linear LDS (row = slot*8 + lane>>3, kbyte = (lane&7)*16)
    // data pre-swizzled at the SOURCE: logical kbyte = ((lane&7)^(lane>>3))<<4
    const int sx = ((lane & 7) ^ (lane >> 3)) << 4;
    const int rowL = lane >> 3;
    const char* Ab = (const char*)A;
    const char* B0b = (const char*)B0;
    const char* B1b = (const char*)B1;
    const size_t ldb = (size_t)KTOT * 2;

    // fragment read addressing (elements), swizzle matches staging
    const int rA = wr * 64 + (lane & 15);
    const int rB = wc * 64 + (lane & 15);
    const int kxorE = (lane & 7) << 3;
    const int kbaseE = (lane >> 4) << 3;

    constexpr int KSTEPS = KTOT / 64;
#pragma unroll 1
    for (int kt = 0; kt < KSTEPS; kt++) {
        const size_t kb = (size_t)kt * 128;
#pragma unroll
        for (int i = 0; i < 4; i++) {
            const int slot = wave * 4 + i;
            const int row = slot * 8 + rowL;
            async_copy16((char*)sA + slot * 1024,
                         Ab + (size_t)(m0 + row) * ldb + kb + sx);
            async_copy16((char*)sB0 + slot * 1024,
                         B0b + (size_t)(n0 + row) * ldb + kb + sx);
            if constexpr (DUAL)
                async_copy16((char*)sB1 + slot * 1024,
                             B1b + (size_t)(n0 + row) * ldb + kb + sx);
        }
        __syncthreads();
#pragma unroll
        for (int ks = 0; ks < 2; ks++) {
            const int kx = (ks * 32 + kbaseE) ^ kxorE;
            short8 a[4];
#pragma unroll
            for (int mi = 0; mi < 4; mi++)
                a[mi] = *(const short8*)&sA[(rA + mi * 16) * 64 + kx];
#pragma unroll
            for (int ni = 0; ni < 4; ni++) {
                const short8 b0 = *(const short8*)&sB0[(rB + ni * 16) * 64 + kx];
#pragma unroll
                for (int mi = 0; mi < 4; mi++)
                    acc0[mi][ni] = __builtin_amdgcn_mfma_f32_16x16x32_bf16(
                        a[mi], b0, acc0[mi][ni], 0, 0, 0);
                if constexpr (DUAL) {
                    const short8 b1 = *(const short8*)&sB1[(rB + ni * 16) * 64 + kx];
#pragma unroll
                    for (int mi = 0; mi < 4; mi++)
                        acc1[mi][ni] = __builtin_amdgcn_mfma_f32_16x16x32_bf16(
                            a[mi], b1, acc1[mi][ni], 0, 0, 0);
                }
            }
        }
        __syncthreads();
    }

    // epilogue: D row = (lane>>4)*4 + j, col = lane&15
    const int mBase = m0 + wr * 64 + ((lane >> 4) << 2);
    const int lBase = n0 + wc * 64 + (lane & 15);
#pragma unroll
    for (int ni = 0; ni < 4; ni++) {
        const int l = lBase + ni * 16;
        if constexpr (DUAL) {
            const float bil = bi[l], bgl = bg[l], bcl = bc[l];
#pragma unroll
            for (int mi = 0; mi < 4; mi++) {
#pragma unroll
                for (int j = 0; j < 4; j++) {
                    const int m = mBase + mi * 16 + j;
                    const size_t idx = (size_t)m * NL + l;
                    const float ipre = acc0[mi][ni][j] + bil;
                    const float fpre = acc1[mi][ni][j] + bgl;
                    const float fv = 1.f / (1.f + __expf(-fpre));
                    const float iv = 1.f / (1.f + __expf(-ipre));
                    const float uv = uio[idx] + bcl;
                    out0[idx] = fv;
                    uio[idx] = iv * uv;
                }
            }
        } else {
#pragma unroll
            for (int mi = 0; mi < 4; mi++) {
#pragma unroll
                for (int j = 0; j < 4; j++) {
                    const int m = mBase + mi * 16 + j;
                    out0[(size_t)m * NL + l] = acc0[mi][ni][j];
                }
            }
        }
    }
}

// ---------------------------------------------------------------------------
// Kernel 3: sequential scan; h = sin(z)*c; out[b,l,t].
// ---------------------------------------------------------------------------
__global__ __launch_bounds__(512) void k3_scan(
    const float* __restrict__ z, const float* __restrict__ fbuf,
    const float* __restrict__ iubuf, const float* __restrict__ init_c,
    float* __restrict__ out)
{
    const int b = blockIdx.x;
    const int l = threadIdx.x;
    float c = init_c[l];

    const float* zpt = z     + (size_t)b * NT * NL + l;
    const float* fpt = fbuf  + (size_t)b * NT * NL + l;
    const float* ipt = iubuf + (size_t)b * NT * NL + l;
    float* op = out + ((size_t)b * NL + l) * NT;

    for (int t0 = 0; t0 < NT; t0 += 16) {
        float h[16];
#pragma unroll
        for (int j = 0; j < 16; j++) {
            const size_t off = (size_t)(t0 + j) * NL;
            const float fv = fpt[off];
            const float iv = ipt[off];
            const float zv = zpt[off];
            c = fv * c + iv;
            h[j] = __sinf(zv) * c;
        }
        float4* o4 = (float4*)(op + t0);
        o4[0] = make_float4(h[0],  h[1],  h[2],  h[3]);
        o4[1] = make_float4(h[4],  h[5],  h[6],  h[7]);
        o4[2] = make_float4(h[8],  h[9],  h[10], h[11]);
        o4[3] = make_float4(h[12], h[13], h[14], h[15]);
    }
}

// ---------------------------------------------------------------------------
extern "C" void kernel_launch(void* const* d_in, const int* in_sizes, int n_in,
                              void* d_out, int out_size, void* d_ws, size_t ws_size,
                              hipStream_t stream)
{
    const float* x      = (const float*)d_in[0];
    const float* conn   = (const float*)d_in[1];
    const float* Wf     = (const float*)d_in[2];
    const float* bfv    = (const float*)d_in[3];
    const float* gamma  = (const float*)d_in[4];
    const float* beta   = (const float*)d_in[5];
    const float* Wi     = (const float*)d_in[6];
    const float* Ri     = (const float*)d_in[7];
    const float* bi     = (const float*)d_in[8];
    const float* Wg     = (const float*)d_in[9];
    const float* Rg     = (const float*)d_in[10];
    const float* bg     = (const float*)d_in[11];
    const float* Wc     = (const float*)d_in[12];
    const float* bc     = (const float*)d_in[13];
    const float* init_h = (const float*)d_in[14];
    const float* init_c = (const float*)d_in[15];

    char* w = (char*)d_ws;
    float* zbuf = (float*)w;                     w += (size_t)M_TOT * NL * 4;
    float* fb   = (float*)w;                     w += (size_t)M_TOT * NL * 4;
    float* ub   = (float*)w;                     w += (size_t)M_TOT * NL * 4;
    __hip_bfloat16* abuf = (__hip_bfloat16*)w;   w += (size_t)M_TOT * 1024 * 2;
    __hip_bfloat16* cbuf = (__hip_bfloat16*)w;   w += (size_t)M_TOT * NCONN * 2;
    __hip_bfloat16* Bti  = (__hip_bfloat16*)w;   w += (size_t)NL * 1024 * 2;
    __hip_bfloat16* Btg  = (__hip_bfloat16*)w;   w += (size_t)NL * 1024 * 2;
    __hip_bfloat16* Btc  = (__hip_bfloat16*)w;   w += (size_t)NL * NCONN * 2;

    // weight prep: Bti = [Wi;Ri]^T, Btg = [Wg;Rg]^T, Btc = Wc^T (all N x K bf16)
    wconv_transpose<<<64, 256, 0, stream>>>(Wi, Bti, 512, 512, 1024, 0);
    wconv_transpose<<<64, 256, 0, stream>>>(Ri, Bti, 512, 512, 1024, 512);
    wconv_transpose<<<64, 256, 0, stream>>>(Wg, Btg, 512, 512, 1024, 0);
    wconv_transpose<<<64, 256, 0, stream>>>(Rg, Btg, 512, 512, 1024, 512);
    wconv_transpose<<<32, 256, 0, stream>>>(Wc, Btc, 256, 512, 256, 0);
    conv_bf16_vec<<<(M_TOT * NCONN / 4 + 255) / 256, 256, 0, stream>>>(
        conn, cbuf, M_TOT * NCONN);

    k1_fourier_ln<<<NB * NT / BT, 512, 0, stream>>>(x, Wf, bfv, gamma, beta,
                                                    init_h, zbuf, abuf);

    // u = conn @ Wc  (bias bc folded into gates epilogue)
    gemm_mfma<256, false><<<dim3(128, 4), 256, 0, stream>>>(
        cbuf, Btc, nullptr, nullptr, nullptr, nullptr, ub, nullptr);

    // gates: f = sigmoid(A@[Wg;Rg]+bg), iu = sigmoid(A@[Wi;Ri]+bi)*(u+bc)
    gemm_mfma<1024, true><<<dim3(128, 4), 256, 0, stream>>>(
        abuf, Bti, Btg, bi, bg, bc, fb, ub);

    k3_scan<<<NB, 512, 0, stream>>>(zbuf, fb, ub, init_c, (float*)d_out);
}

// Round 3
// 211.021 us; speedup vs baseline: 3.7994x; 1.5179x over previous
//
#include <hip/hip_runtime.h>
#include <hip/hip_bf16.h>

#define NB 32
#define IN_DIM 256
#define NT 512
#define NL 512
#define NCONN 256
#define BT 16
#define LN_EPS 1e-3f
#define M_TOT (NB * NT)   // 16384 rows

typedef __attribute__((ext_vector_type(8))) short short8;
typedef __attribute__((ext_vector_type(16))) float f32x16;

__device__ __forceinline__ void async_copy16(void* lds_dst, const void* g_src) {
    __builtin_amdgcn_global_load_lds(
        (const __attribute__((address_space(1))) unsigned int*)g_src,
        (__attribute__((address_space(3))) unsigned int*)lds_dst, 16, 0, 0);
}

// ---------------------------------------------------------------------------
// Kernel 1: z = LN(cos(xt @ Wf + bf)); writes A = [z | z_prev] bf16 only.
// ---------------------------------------------------------------------------
__global__ __launch_bounds__(512) void k1_fourier_ln(
    const float* __restrict__ x, const float* __restrict__ Wf,
    const float* __restrict__ bf, const float* __restrict__ gamma,
    const float* __restrict__ beta, const float* __restrict__ init_h,
    __hip_bfloat16* __restrict__ abuf)
{
    __shared__ float xs[IN_DIM][BT];
    __shared__ float redS[BT][8], redQ[BT][8];
    __shared__ float redM[BT], redR[BT];

    const int blk = blockIdx.x;
    const int b  = blk / (NT / BT);
    const int t0 = (blk % (NT / BT)) * BT;
    const int tid = threadIdx.x;

    for (int i = tid; i < IN_DIM * BT; i += 512) {
        const int r = i & (BT - 1), k = i / BT;
        xs[k][r] = x[((size_t)b * IN_DIM + k) * NT + t0 + r];
    }
    __syncthreads();

    const int l = tid;
    float acc[BT];
#pragma unroll
    for (int r = 0; r < BT; r++) acc[r] = 0.f;

    const float* wp = Wf + l;
    for (int k = 0; k < IN_DIM; k++) {
        const float w = wp[k * NL];
#pragma unroll
        for (int q = 0; q < BT / 4; q++) {
            const float4 a = *(const float4*)&xs[k][q * 4];
            acc[q * 4 + 0] += a.x * w; acc[q * 4 + 1] += a.y * w;
            acc[q * 4 + 2] += a.z * w; acc[q * 4 + 3] += a.w * w;
        }
    }

    const float bfl = bf[l];
    float p[BT], s1[BT], s2[BT];
#pragma unroll
    for (int r = 0; r < BT; r++) {
        p[r] = __cosf(acc[r] + bfl);
        s1[r] = p[r];
        s2[r] = p[r] * p[r];
    }
#pragma unroll
    for (int off = 32; off >= 1; off >>= 1) {
#pragma unroll
        for (int r = 0; r < BT; r++) {
            s1[r] += __shfl_xor(s1[r], off);
            s2[r] += __shfl_xor(s2[r], off);
        }
    }
    const int wave = tid >> 6, lane = tid & 63;
    if (lane == 0) {
#pragma unroll
        for (int r = 0; r < BT; r++) { redS[r][wave] = s1[r]; redQ[r][wave] = s2[r]; }
    }
    __syncthreads();
    if (tid < BT) {
        float a = 0.f, q = 0.f;
#pragma unroll
        for (int w = 0; w < 8; w++) { a += redS[tid][w]; q += redQ[tid][w]; }
        const float mu = a * (1.0f / NL);
        const float var = q * (1.0f / NL) - mu * mu;
        redM[tid] = mu;
        redR[tid] = rsqrtf(var + LN_EPS);
    }
    __syncthreads();

    const float g = gamma[l], be = beta[l];
#pragma unroll
    for (int r = 0; r < BT; r++) {
        const float zv = g * (p[r] - redM[r]) * redR[r] + be;
        const int t = t0 + r;
        const size_t m = (size_t)b * NT + t;
        const __hip_bfloat16 zb = __float2bfloat16(zv);
        abuf[m * 1024 + l] = zb;                                // A[:,0:512] = z_t
        if (t < NT - 1) abuf[(m + 1) * 1024 + 512 + l] = zb;    // A[t+1,512:] = z_t
    }
    if (t0 == 0) abuf[(size_t)b * NT * 1024 + 512 + l] = __float2bfloat16(init_h[l]);
}

// ---------------------------------------------------------------------------
// Weight transpose+convert: dst[n][k_off+k] = bf16(src[k][n]); src is K x N.
// ---------------------------------------------------------------------------
__global__ __launch_bounds__(256) void wconv_transpose(
    const float* __restrict__ src, __hip_bfloat16* __restrict__ dst,
    int K, int N, int lddst, int k_off)
{
    __shared__ float t[64][65];
    const int ntn = N >> 6;
    const int k0 = (blockIdx.x / ntn) << 6;
    const int n0 = (blockIdx.x % ntn) << 6;
    const int tid = threadIdx.x;
    for (int idx = tid; idx < 4096; idx += 256) {
        const int kk = idx >> 6, nn = idx & 63;
        t[kk][nn] = src[(size_t)(k0 + kk) * N + n0 + nn];
    }
    __syncthreads();
    for (int idx = tid; idx < 4096; idx += 256) {
        const int nn = idx >> 6, kk = idx & 63;
        dst[(size_t)(n0 + nn) * lddst + k_off + k0 + kk] = __float2bfloat16(t[kk][nn]);
    }
}

__global__ __launch_bounds__(256) void conv_bf16_vec(
    const float* __restrict__ src, __hip_bfloat16* __restrict__ dst, int n)
{
    const int e = (blockIdx.x * 256 + threadIdx.x) * 4;
    if (e < n) {
        const float4 v = *(const float4*)(src + e);
        dst[e + 0] = __float2bfloat16(v.x);
        dst[e + 1] = __float2bfloat16(v.y);
        dst[e + 2] = __float2bfloat16(v.z);
        dst[e + 3] = __float2bfloat16(v.w);
    }
}

// ---------------------------------------------------------------------------
// MFMA GEMM: 256x128 tile, BK=64, 8 waves (wave-tile 64x64, 32x32x16 frags),
// double-buffered LDS with stage-ahead. A: M x KTOT bf16, B: N x KTOT bf16.
// DUAL: acc0=A@Bi^T, acc1=A@Bg^T; epilogue f=sig(acc1+bg)->fb,
//       iu=sig(acc0+bi)*u (u read from ub) -> ub.   (bf16 outputs)
// !DUAL: ub = bf16(A@B0^T + bc).
// ---------------------------------------------------------------------------
template<int KTOT, bool DUAL>
__global__ __launch_bounds__(512, 2) void gemm_mfma(
    const __hip_bfloat16* __restrict__ A,
    const __hip_bfloat16* __restrict__ B0,
    const __hip_bfloat16* __restrict__ B1,
    const float* __restrict__ bi, const float* __restrict__ bg,
    const float* __restrict__ bc,
    __hip_bfloat16* __restrict__ fb, __hip_bfloat16* __restrict__ ub)
{
    constexpr int ABYTES = 256 * 128;                    // 32 KB
    constexpr int BBYTES = 128 * 128;                    // 16 KB
    constexpr int NBUFB  = ABYTES + (DUAL ? 2 : 1) * BBYTES;
    __shared__ __align__(16) char lds[2 * NBUFB];

    const int tid  = threadIdx.x;
    const int wave = tid >> 6, lane = tid & 63;
    const int wm = wave >> 1, wn = wave & 1;             // 4 x 2 wave grid
    const int m0 = blockIdx.x * 256;
    const int n0 = blockIdx.y * 128;

    f32x16 acc0[2][2];
    f32x16 acc1[DUAL ? 2 : 1][DUAL ? 2 : 1];
#pragma unroll
    for (int mi = 0; mi < 2; mi++)
#pragma unroll
        for (int ni = 0; ni < 2; ni++) {
            acc0[mi][ni] = (f32x16)0.f;
            if constexpr (DUAL) acc1[mi][ni] = (f32x16)0.f;
        }

    // staging addressing: idx = j*512+tid; row = idx>>3; slot = tid&7;
    // source pre-swizzled so that LDS stays linear (both-sides involution)
    const int rowq = tid >> 3;                           // row within 64-row group
    const int sswz = (((tid & 7) ^ (rowq & 7)) << 4);    // source byte swizzle
    const char* Ab  = (const char*)A;
    const char* B0b = (const char*)B0;
    const char* B1b = (const char*)B1;
    constexpr size_t ldk = (size_t)KTOT * 2;

    auto stage = [&](int buf, int kt) {
        const size_t kb = (size_t)kt * 128;
        char* base = lds + buf * NBUFB;
#pragma unroll
        for (int j = 0; j < 4; j++) {                    // A: 256 rows
            const int row = j * 64 + rowq;
            async_copy16(base + (j * 512 + tid) * 16,
                         Ab + (size_t)(m0 + row) * ldk + kb + sswz);
        }
#pragma unroll
        for (int j = 0; j < 2; j++) {                    // B: 128 rows
            const int row = j * 64 + rowq;
            async_copy16(base + ABYTES + (j * 512 + tid) * 16,
                         B0b + (size_t)(n0 + row) * ldk + kb + sswz);
            if constexpr (DUAL)
                async_copy16(base + ABYTES + BBYTES + (j * 512 + tid) * 16,
                             B1b + (size_t)(n0 + row) * ldk + kb + sswz);
        }
    };

    // fragment addressing: row ≡ lane&7 (mod 8) for all frags -> uniform XOR
    const int ra = wm * 64 + (lane & 31);
    const int rb = wn * 64 + (lane & 31);
    const int khalf = (lane >> 5) << 4;                  // byte offset of k-half
    const int swz = (lane & 7) << 4;

    constexpr int KSTEPS = KTOT / 64;
    stage(0, 0);
    int cur = 0;
#pragma unroll 1
    for (int kt = 0; kt < KSTEPS; kt++) {
        __syncthreads();                                 // buf[cur] ready
        if (kt + 1 < KSTEPS) stage(cur ^ 1, kt + 1);     // overlap with compute
        const char* sA  = lds + cur * NBUFB;
        const char* sB0 = sA + ABYTES;
        const char* sB1 = sB0 + BBYTES;
#pragma unroll
        for (int ks = 0; ks < 4; ks++) {
            const int kx = (ks * 32 + khalf) ^ swz;
            short8 a[2], b0[2];
#pragma unroll
            for (int mi = 0; mi < 2; mi++)
                a[mi] = *(const short8*)(sA + (size_t)(ra + mi * 32) * 128 + kx);
#pragma unroll
            for (int ni = 0; ni < 2; ni++)
                b0[ni] = *(const short8*)(sB0 + (size_t)(rb + ni * 32) * 128 + kx);
#pragma unroll
            for (int ni = 0; ni < 2; ni++)
#pragma unroll
                for (int mi = 0; mi < 2; mi++)
                    acc0[mi][ni] = __builtin_amdgcn_mfma_f32_32x32x16_bf16(
                        a[mi], b0[ni], acc0[mi][ni], 0, 0, 0);
            if constexpr (DUAL) {
                short8 b1[2];
#pragma unroll
                for (int ni = 0; ni < 2; ni++)
                    b1[ni] = *(const short8*)(sB1 + (size_t)(rb + ni * 32) * 128 + kx);
#pragma unroll
                for (int ni = 0; ni < 2; ni++)
#pragma unroll
                    for (int mi = 0; mi < 2; mi++)
                        acc1[mi][ni] = __builtin_amdgcn_mfma_f32_32x32x16_bf16(
                            a[mi], b1[ni], acc1[mi][ni], 0, 0, 0);
            }
        }
        cur ^= 1;
    }

    // epilogue: C/D layout col=lane&31, row=(r&3)+8*(r>>2)+4*(lane>>5)
#pragma unroll
    for (int ni = 0; ni < 2; ni++) {
        const int l = n0 + wn * 64 + ni * 32 + (lane & 31);
        float bil = 0.f, bgl = 0.f, bcl = 0.f;
        if constexpr (DUAL) { bil = bi[l]; bgl = bg[l]; }
        else                { bcl = bc[l]; }
#pragma unroll
        for (int mi = 0; mi < 2; mi++) {
#pragma unroll
            for (int r = 0; r < 16; r++) {
                const int m = m0 + wm * 64 + mi * 32 +
                              (r & 3) + 8 * (r >> 2) + 4 * (lane >> 5);
                const size_t idx = (size_t)m * NL + l;
                if constexpr (DUAL) {
                    const float ipre = acc0[mi][ni][r] + bil;
                    const float fpre = acc1[mi][ni][r] + bgl;
                    const float fv = 1.f / (1.f + __expf(-fpre));
                    const float iv = 1.f / (1.f + __expf(-ipre));
                    const float uv = __bfloat162float(ub[idx]);
                    fb[idx] = __float2bfloat16(fv);
                    ub[idx] = __float2bfloat16(iv * uv);
                } else {
                    ub[idx] = __float2bfloat16(acc0[mi][ni][r] + bcl);
                }
            }
        }
    }
}

// ---------------------------------------------------------------------------
// Kernel 3: sequential scan; h = sin(z)*c; out[b,l,t]. All inputs bf16.
// ---------------------------------------------------------------------------
__global__ __launch_bounds__(64) void k3_scan(
    const __hip_bfloat16* __restrict__ zab,   // abuf: z at [m*1024 + l]
    const __hip_bfloat16* __restrict__ fb,
    const __hip_bfloat16* __restrict__ ub,
    const float* __restrict__ init_c, float* __restrict__ out)
{
    const int b = blockIdx.x >> 3;
    const int l = ((blockIdx.x & 7) << 6) + threadIdx.x;
    float c = init_c[l];

    const __hip_bfloat16* zp = zab + (size_t)b * NT * 1024 + l;
    const __hip_bfloat16* fp = fb  + (size_t)b * NT * NL + l;
    const __hip_bfloat16* ip = ub  + (size_t)b * NT * NL + l;
    float* op = out + ((size_t)b * NL + l) * NT;

    for (int t0 = 0; t0 < NT; t0 += 16) {
        float fv[16], iv[16], zv[16];
#pragma unroll
        for (int j = 0; j < 16; j++) {
            fv[j] = __bfloat162float(fp[(size_t)(t0 + j) * NL]);
            iv[j] = __bfloat162float(ip[(size_t)(t0 + j) * NL]);
            zv[j] = __bfloat162float(zp[(size_t)(t0 + j) * 1024]);
        }
        float h[16];
#pragma unroll
        for (int j = 0; j < 16; j++) {
            c = fv[j] * c + iv[j];
            h[j] = __sinf(zv[j]) * c;
        }
        float4* o4 = (float4*)(op + t0);
        o4[0] = make_float4(h[0],  h[1],  h[2],  h[3]);
        o4[1] = make_float4(h[4],  h[5],  h[6],  h[7]);
        o4[2] = make_float4(h[8],  h[9],  h[10], h[11]);
        o4[3] = make_float4(h[12], h[13], h[14], h[15]);
    }
}

// ---------------------------------------------------------------------------
extern "C" void kernel_launch(void* const* d_in, const int* in_sizes, int n_in,
                              void* d_out, int out_size, void* d_ws, size_t ws_size,
                              hipStream_t stream)
{
    const float* x      = (const float*)d_in[0];
    const float* conn   = (const float*)d_in[1];
    const float* Wf     = (const float*)d_in[2];
    const float* bfv    = (const float*)d_in[3];
    const float* gamma  = (const float*)d_in[4];
    const float* beta   = (const float*)d_in[5];
    const float* Wi     = (const float*)d_in[6];
    const float* Ri     = (const float*)d_in[7];
    const float* bi     = (const float*)d_in[8];
    const float* Wg     = (const float*)d_in[9];
    const float* Rg     = (const float*)d_in[10];
    const float* bg     = (const float*)d_in[11];
    const float* Wc     = (const float*)d_in[12];
    const float* bc     = (const float*)d_in[13];
    const float* init_h = (const float*)d_in[14];
    const float* init_c = (const float*)d_in[15];

    char* w = (char*)d_ws;
    __hip_bfloat16* abuf = (__hip_bfloat16*)w;  w += (size_t)M_TOT * 1024 * 2;
    __hip_bfloat16* cbuf = (__hip_bfloat16*)w;  w += (size_t)M_TOT * NCONN * 2;
    __hip_bfloat16* fbuf = (__hip_bfloat16*)w;  w += (size_t)M_TOT * NL * 2;
    __hip_bfloat16* ubuf = (__hip_bfloat16*)w;  w += (size_t)M_TOT * NL * 2;
    __hip_bfloat16* Bti  = (__hip_bfloat16*)w;  w += (size_t)NL * 1024 * 2;
    __hip_bfloat16* Btg  = (__hip_bfloat16*)w;  w += (size_t)NL * 1024 * 2;
    __hip_bfloat16* Btc  = (__hip_bfloat16*)w;  w += (size_t)NL * NCONN * 2;

    // weight prep: Bti = [Wi;Ri]^T, Btg = [Wg;Rg]^T, Btc = Wc^T (N x K bf16)
    wconv_transpose<<<64, 256, 0, stream>>>(Wi, Bti, 512, 512, 1024, 0);
    wconv_transpose<<<64, 256, 0, stream>>>(Ri, Bti, 512, 512, 1024, 512);
    wconv_transpose<<<64, 256, 0, stream>>>(Wg, Btg, 512, 512, 1024, 0);
    wconv_transpose<<<64, 256, 0, stream>>>(Rg, Btg, 512, 512, 1024, 512);
    wconv_transpose<<<32, 256, 0, stream>>>(Wc, Btc, 256, 512, 256, 0);
    conv_bf16_vec<<<(M_TOT * NCONN / 4 + 255) / 256, 256, 0, stream>>>(
        conn, cbuf, M_TOT * NCONN);

    k1_fourier_ln<<<NB * NT / BT, 512, 0, stream>>>(x, Wf, bfv, gamma, beta,
                                                    init_h, abuf);

    // u = conn @ Wc + bc  -> ubuf (bf16)
    gemm_mfma<NCONN, false><<<dim3(M_TOT / 256, NL / 128), 512, 0, stream>>>(
        cbuf, Btc, nullptr, nullptr, nullptr, bc, nullptr, ubuf);

    // gates: fbuf = sigmoid(A@Bti^T+bg)... (f), ubuf = sigmoid(.+bi)*u (iu)
    gemm_mfma<1024, true><<<dim3(M_TOT / 256, NL / 128), 512, 0, stream>>>(
        abuf, Bti, Btg, bi, bg, nullptr, fbuf, ubuf);

    k3_scan<<<NB * 8, 64, 0, stream>>>(abuf, fbuf, ubuf, init_c, (float*)d_out);
}

// Round 4
// 155.469 us; speedup vs baseline: 5.1570x; 1.3573x over previous
//
#include <hip/hip_runtime.h>
#include <hip/hip_bf16.h>

#define NB 32
#define IN_DIM 256
#define NT 512
#define NL 512
#define NCONN 256
#define LN_EPS 1e-3f
#define M_TOT (NB * NT)   // 16384 rows

typedef __attribute__((ext_vector_type(8))) short short8;
typedef __attribute__((ext_vector_type(16))) float f32x16;

__device__ __forceinline__ void async_copy16(void* lds_dst, const void* g_src) {
    __builtin_amdgcn_global_load_lds(
        (const __attribute__((address_space(1))) unsigned int*)g_src,
        (__attribute__((address_space(3))) unsigned int*)lds_dst, 16, 0, 0);
}

// ---------------------------------------------------------------------------
// x prep: Axt[b*512+t][k] = bf16(x[b][k][t])   (batched 64x64 LDS transpose)
// ---------------------------------------------------------------------------
__global__ __launch_bounds__(256) void xprep_transpose(
    const float* __restrict__ x, __hip_bfloat16* __restrict__ Axt)
{
    __shared__ float t[64][65];
    const int tilesPerB = (IN_DIM / 64) * (NT / 64);      // 4*8 = 32
    const int b  = blockIdx.x / tilesPerB;
    const int tl = blockIdx.x % tilesPerB;
    const int k0 = (tl / (NT / 64)) * 64;
    const int t0 = (tl % (NT / 64)) * 64;
    const int tid = threadIdx.x;
    const float* src = x + (size_t)b * IN_DIM * NT;
    for (int idx = tid; idx < 4096; idx += 256) {
        const int kk = idx >> 6, tt = idx & 63;
        t[kk][tt] = src[(size_t)(k0 + kk) * NT + t0 + tt];
    }
    __syncthreads();
    for (int idx = tid; idx < 4096; idx += 256) {
        const int tt = idx >> 6, kk = idx & 63;
        Axt[((size_t)b * NT + t0 + tt) * IN_DIM + k0 + kk] =
            __float2bfloat16(t[kk][tt]);
    }
}

__global__ void fill_init_h(const float* __restrict__ init_h,
                            __hip_bfloat16* __restrict__ abuf)
{
    const int l = threadIdx.x;
    const __hip_bfloat16 v = __float2bfloat16(init_h[l]);
    for (int b = 0; b < NB; b++)
        abuf[((size_t)b * NT) * 1024 + 512 + l] = v;
}

// ---------------------------------------------------------------------------
// Kernel 1 (MFMA): P = Axt @ WfT^T  (64 rows x 512 cols per block, K=256),
// p = cos(P+bf), LN over cols, write abuf = [z | z_prev] bf16.
// ---------------------------------------------------------------------------
__global__ __launch_bounds__(512, 1) void k1_mfma_fourier_ln(
    const __hip_bfloat16* __restrict__ Axt,   // [M_TOT][256]
    const __hip_bfloat16* __restrict__ WfT,   // [512][256]
    const float* __restrict__ bf, const float* __restrict__ gamma,
    const float* __restrict__ beta,
    __hip_bfloat16* __restrict__ abuf)
{
    constexpr int ABYTES = 64 * 128;          // 8 KB
    constexpr int BBYTES = 512 * 128;         // 64 KB
    constexpr int NBUFB  = ABYTES + BBYTES;
    __shared__ __align__(16) char lds[2 * NBUFB];     // 144 KB
    __shared__ float pS[64][8], pQ[64][8];
    __shared__ float mS[64], rS[64];

    const int tid  = threadIdx.x;
    const int wave = tid >> 6, lane = tid & 63;
    const int m0 = blockIdx.x * 64;

    f32x16 acc[2][2];
#pragma unroll
    for (int mi = 0; mi < 2; mi++)
#pragma unroll
        for (int ni = 0; ni < 2; ni++) acc[mi][ni] = (f32x16)0.f;

    const int rowq = tid >> 3;
    const int sswz = ((tid & 7) ^ (rowq & 7)) << 4;
    const char* Ab = (const char*)Axt;
    const char* Bb = (const char*)WfT;

    auto stage = [&](int buf, int kt) {
        const size_t kb = (size_t)kt * 128;
        char* base = lds + buf * NBUFB;
        async_copy16(base + tid * 16,
                     Ab + (size_t)(m0 + rowq) * 512 + kb + sswz);
#pragma unroll
        for (int j = 0; j < 8; j++) {
            const int row = j * 64 + rowq;
            async_copy16(base + ABYTES + (j * 512 + tid) * 16,
                         Bb + (size_t)row * 512 + kb + sswz);
        }
    };

    const int ra = lane & 31;
    const int khalf = (lane >> 5) << 4;
    const int swz = (lane & 7) << 4;

    stage(0, 0);
    int cur = 0;
#pragma unroll 1
    for (int kt = 0; kt < 4; kt++) {
        __syncthreads();
        if (kt + 1 < 4) stage(cur ^ 1, kt + 1);
        const char* sA = lds + cur * NBUFB;
        const char* sB = sA + ABYTES;
#pragma unroll
        for (int ks = 0; ks < 4; ks++) {
            const int kx = (ks * 32 + khalf) ^ swz;
            short8 a[2], b[2];
#pragma unroll
            for (int mi = 0; mi < 2; mi++)
                a[mi] = *(const short8*)(sA + (size_t)(ra + mi * 32) * 128 + kx);
#pragma unroll
            for (int ni = 0; ni < 2; ni++)
                b[ni] = *(const short8*)(sB +
                    (size_t)(wave * 64 + ni * 32 + (lane & 31)) * 128 + kx);
#pragma unroll
            for (int ni = 0; ni < 2; ni++)
#pragma unroll
                for (int mi = 0; mi < 2; mi++)
                    acc[mi][ni] = __builtin_amdgcn_mfma_f32_32x32x16_bf16(
                        a[mi], b[ni], acc[mi][ni], 0, 0, 0);
        }
        cur ^= 1;
    }

    // ---- LN epilogue ----
    int cg[2]; float bfc[2];
#pragma unroll
    for (int ni = 0; ni < 2; ni++) {
        cg[ni] = wave * 64 + ni * 32 + (lane & 31);
        bfc[ni] = bf[cg[ni]];
    }
    const int rhi = 4 * (lane >> 5);

#pragma unroll
    for (int mi = 0; mi < 2; mi++) {
#pragma unroll
        for (int r = 0; r < 16; r++) {
            const float p0 = __cosf(acc[mi][0][r] + bfc[0]);
            const float p1 = __cosf(acc[mi][1][r] + bfc[1]);
            float s = p0 + p1;
            float q = p0 * p0 + p1 * p1;
#pragma unroll
            for (int off = 16; off >= 1; off >>= 1) {
                s += __shfl_xor(s, off);
                q += __shfl_xor(q, off);
            }
            if ((lane & 31) == 0) {
                const int row = mi * 32 + (r & 3) + 8 * (r >> 2) + rhi;
                pS[row][wave] = s;
                pQ[row][wave] = q;
            }
        }
    }
    __syncthreads();
    if (tid < 64) {
        float a = 0.f, qq = 0.f;
#pragma unroll
        for (int w = 0; w < 8; w++) { a += pS[tid][w]; qq += pQ[tid][w]; }
        const float mu = a * (1.0f / NL);
        const float var = qq * (1.0f / NL) - mu * mu;
        mS[tid] = mu;
        rS[tid] = rsqrtf(var + LN_EPS);
    }
    __syncthreads();

    float gm[2], bt[2];
#pragma unroll
    for (int ni = 0; ni < 2; ni++) { gm[ni] = gamma[cg[ni]]; bt[ni] = beta[cg[ni]]; }

#pragma unroll
    for (int mi = 0; mi < 2; mi++) {
#pragma unroll
        for (int r = 0; r < 16; r++) {
            const int row = mi * 32 + (r & 3) + 8 * (r >> 2) + rhi;
            const int m = m0 + row;
            const int t = m & (NT - 1);
            const float mu = mS[row], rs = rS[row];
#pragma unroll
            for (int ni = 0; ni < 2; ni++) {
                const float p = __cosf(acc[mi][ni][r] + bfc[ni]);
                const float z = gm[ni] * (p - mu) * rs + bt[ni];
                const __hip_bfloat16 zb = __float2bfloat16(z);
                abuf[(size_t)m * 1024 + cg[ni]] = zb;
                if (t != NT - 1) abuf[(size_t)(m + 1) * 1024 + 512 + cg[ni]] = zb;
            }
        }
    }
}

// ---------------------------------------------------------------------------
// Weight transpose+convert: dst[n][k_off+k] = bf16(src[k][n]); src is K x N.
// ---------------------------------------------------------------------------
__global__ __launch_bounds__(256) void wconv_transpose(
    const float* __restrict__ src, __hip_bfloat16* __restrict__ dst,
    int K, int N, int lddst, int k_off)
{
    __shared__ float t[64][65];
    const int ntn = N >> 6;
    const int k0 = (blockIdx.x / ntn) << 6;
    const int n0 = (blockIdx.x % ntn) << 6;
    const int tid = threadIdx.x;
    for (int idx = tid; idx < 4096; idx += 256) {
        const int kk = idx >> 6, nn = idx & 63;
        t[kk][nn] = src[(size_t)(k0 + kk) * N + n0 + nn];
    }
    __syncthreads();
    for (int idx = tid; idx < 4096; idx += 256) {
        const int nn = idx >> 6, kk = idx & 63;
        dst[(size_t)(n0 + nn) * lddst + k_off + k0 + kk] = __float2bfloat16(t[kk][nn]);
    }
}

__global__ __launch_bounds__(256) void conv_bf16_vec(
    const float* __restrict__ src, __hip_bfloat16* __restrict__ dst, int n)
{
    const int e = (blockIdx.x * 256 + threadIdx.x) * 4;
    if (e < n) {
        const float4 v = *(const float4*)(src + e);
        dst[e + 0] = __float2bfloat16(v.x);
        dst[e + 1] = __float2bfloat16(v.y);
        dst[e + 2] = __float2bfloat16(v.z);
        dst[e + 3] = __float2bfloat16(v.w);
    }
}

// ---------------------------------------------------------------------------
// MFMA GEMM: 256x128 tile, BK=64, 8 waves, double-buffered stage-ahead.
// DUAL: f=sig(A@Bg^T+bg)->fb, iu=sig(A@Bi^T+bi)*u->ub.  !DUAL: ub=A@B0^T+bc.
// ---------------------------------------------------------------------------
template<int KTOT, bool DUAL>
__global__ __launch_bounds__(512, 2) void gemm_mfma(
    const __hip_bfloat16* __restrict__ A,
    const __hip_bfloat16* __restrict__ B0,
    const __hip_bfloat16* __restrict__ B1,
    const float* __restrict__ bi, const float* __restrict__ bg,
    const float* __restrict__ bc,
    __hip_bfloat16* __restrict__ fb, __hip_bfloat16* __restrict__ ub)
{
    constexpr int ABYTES = 256 * 128;
    constexpr int BBYTES = 128 * 128;
    constexpr int NBUFB  = ABYTES + (DUAL ? 2 : 1) * BBYTES;
    __shared__ __align__(16) char lds[2 * NBUFB];

    const int tid  = threadIdx.x;
    const int wave = tid >> 6, lane = tid & 63;
    const int wm = wave >> 1, wn = wave & 1;
    const int m0 = blockIdx.x * 256;
    const int n0 = blockIdx.y * 128;

    f32x16 acc0[2][2];
    f32x16 acc1[DUAL ? 2 : 1][DUAL ? 2 : 1];
#pragma unroll
    for (int mi = 0; mi < 2; mi++)
#pragma unroll
        for (int ni = 0; ni < 2; ni++) {
            acc0[mi][ni] = (f32x16)0.f;
            if constexpr (DUAL) acc1[mi][ni] = (f32x16)0.f;
        }

    const int rowq = tid >> 3;
    const int sswz = (((tid & 7) ^ (rowq & 7)) << 4);
    const char* Ab  = (const char*)A;
    const char* B0b = (const char*)B0;
    const char* B1b = (const char*)B1;
    constexpr size_t ldk = (size_t)KTOT * 2;

    auto stage = [&](int buf, int kt) {
        const size_t kb = (size_t)kt * 128;
        char* base = lds + buf * NBUFB;
#pragma unroll
        for (int j = 0; j < 4; j++) {
            const int row = j * 64 + rowq;
            async_copy16(base + (j * 512 + tid) * 16,
                         Ab + (size_t)(m0 + row) * ldk + kb + sswz);
        }
#pragma unroll
        for (int j = 0; j < 2; j++) {
            const int row = j * 64 + rowq;
            async_copy16(base + ABYTES + (j * 512 + tid) * 16,
                         B0b + (size_t)(n0 + row) * ldk + kb + sswz);
            if constexpr (DUAL)
                async_copy16(base + ABYTES + BBYTES + (j * 512 + tid) * 16,
                             B1b + (size_t)(n0 + row) * ldk + kb + sswz);
        }
    };

    const int ra = wm * 64 + (lane & 31);
    const int rb = wn * 64 + (lane & 31);
    const int khalf = (lane >> 5) << 4;
    const int swz = (lane & 7) << 4;

    constexpr int KSTEPS = KTOT / 64;
    stage(0, 0);
    int cur = 0;
#pragma unroll 1
    for (int kt = 0; kt < KSTEPS; kt++) {
        __syncthreads();
        if (kt + 1 < KSTEPS) stage(cur ^ 1, kt + 1);
        const char* sA  = lds + cur * NBUFB;
        const char* sB0 = sA + ABYTES;
        const char* sB1 = sB0 + BBYTES;
#pragma unroll
        for (int ks = 0; ks < 4; ks++) {
            const int kx = (ks * 32 + khalf) ^ swz;
            short8 a[2], b0[2];
#pragma unroll
            for (int mi = 0; mi < 2; mi++)
                a[mi] = *(const short8*)(sA + (size_t)(ra + mi * 32) * 128 + kx);
#pragma unroll
            for (int ni = 0; ni < 2; ni++)
                b0[ni] = *(const short8*)(sB0 + (size_t)(rb + ni * 32) * 128 + kx);
#pragma unroll
            for (int ni = 0; ni < 2; ni++)
#pragma unroll
                for (int mi = 0; mi < 2; mi++)
                    acc0[mi][ni] = __builtin_amdgcn_mfma_f32_32x32x16_bf16(
                        a[mi], b0[ni], acc0[mi][ni], 0, 0, 0);
            if constexpr (DUAL) {
                short8 b1[2];
#pragma unroll
                for (int ni = 0; ni < 2; ni++)
                    b1[ni] = *(const short8*)(sB1 + (size_t)(rb + ni * 32) * 128 + kx);
#pragma unroll
                for (int ni = 0; ni < 2; ni++)
#pragma unroll
                    for (int mi = 0; mi < 2; mi++)
                        acc1[mi][ni] = __builtin_amdgcn_mfma_f32_32x32x16_bf16(
                            a[mi], b1[ni], acc1[mi][ni], 0, 0, 0);
            }
        }
        cur ^= 1;
    }

#pragma unroll
    for (int ni = 0; ni < 2; ni++) {
        const int l = n0 + wn * 64 + ni * 32 + (lane & 31);
        float bil = 0.f, bgl = 0.f, bcl = 0.f;
        if constexpr (DUAL) { bil = bi[l]; bgl = bg[l]; }
        else                { bcl = bc[l]; }
#pragma unroll
        for (int mi = 0; mi < 2; mi++) {
#pragma unroll
            for (int r = 0; r < 16; r++) {
                const int m = m0 + wm * 64 + mi * 32 +
                              (r & 3) + 8 * (r >> 2) + 4 * (lane >> 5);
                const size_t idx = (size_t)m * NL + l;
                if constexpr (DUAL) {
                    const float ipre = acc0[mi][ni][r] + bil;
                    const float fpre = acc1[mi][ni][r] + bgl;
                    const float fv = 1.f / (1.f + __expf(-fpre));
                    const float iv = 1.f / (1.f + __expf(-ipre));
                    const float uv = __bfloat162float(ub[idx]);
                    fb[idx] = __float2bfloat16(fv);
                    ub[idx] = __float2bfloat16(iv * uv);
                } else {
                    ub[idx] = __float2bfloat16(acc0[mi][ni][r] + bcl);
                }
            }
        }
    }
}

// ---------------------------------------------------------------------------
// Kernel 3: sequential scan; h = sin(z)*c; out[b,l,t].
// ---------------------------------------------------------------------------
__global__ __launch_bounds__(64) void k3_scan(
    const __hip_bfloat16* __restrict__ zab,
    const __hip_bfloat16* __restrict__ fb,
    const __hip_bfloat16* __restrict__ ub,
    const float* __restrict__ init_c, float* __restrict__ out)
{
    const int b = blockIdx.x >> 3;
    const int l = ((blockIdx.x & 7) << 6) + threadIdx.x;
    float c = init_c[l];

    const __hip_bfloat16* zp = zab + (size_t)b * NT * 1024 + l;
    const __hip_bfloat16* fp = fb  + (size_t)b * NT * NL + l;
    const __hip_bfloat16* ip = ub  + (size_t)b * NT * NL + l;
    float* op = out + ((size_t)b * NL + l) * NT;

    for (int t0 = 0; t0 < NT; t0 += 16) {
        float fv[16], iv[16], zv[16];
#pragma unroll
        for (int j = 0; j < 16; j++) {
            fv[j] = __bfloat162float(fp[(size_t)(t0 + j) * NL]);
            iv[j] = __bfloat162float(ip[(size_t)(t0 + j) * NL]);
            zv[j] = __bfloat162float(zp[(size_t)(t0 + j) * 1024]);
        }
        float h[16];
#pragma unroll
        for (int j = 0; j < 16; j++) {
            c = fv[j] * c + iv[j];
            h[j] = __sinf(zv[j]) * c;
        }
        float4* o4 = (float4*)(op + t0);
        o4[0] = make_float4(h[0],  h[1],  h[2],  h[3]);
        o4[1] = make_float4(h[4],  h[5],  h[6],  h[7]);
        o4[2] = make_float4(h[8],  h[9],  h[10], h[11]);
        o4[3] = make_float4(h[12], h[13], h[14], h[15]);
    }
}

// ---------------------------------------------------------------------------
extern "C" void kernel_launch(void* const* d_in, const int* in_sizes, int n_in,
                              void* d_out, int out_size, void* d_ws, size_t ws_size,
                              hipStream_t stream)
{
    const float* x      = (const float*)d_in[0];
    const float* conn   = (const float*)d_in[1];
    const float* Wf     = (const float*)d_in[2];
    const float* bfv    = (const float*)d_in[3];
    const float* gamma  = (const float*)d_in[4];
    const float* beta   = (const float*)d_in[5];
    const float* Wi     = (const float*)d_in[6];
    const float* Ri     = (const float*)d_in[7];
    const float* bi     = (const float*)d_in[8];
    const float* Wg     = (const float*)d_in[9];
    const float* Rg     = (const float*)d_in[10];
    const float* bg     = (const float*)d_in[11];
    const float* Wc     = (const float*)d_in[12];
    const float* bc     = (const float*)d_in[13];
    const float* init_h = (const float*)d_in[14];
    const float* init_c = (const float*)d_in[15];

    char* w = (char*)d_ws;
    __hip_bfloat16* abuf = (__hip_bfloat16*)w;  w += (size_t)M_TOT * 1024 * 2;
    __hip_bfloat16* cbuf = (__hip_bfloat16*)w;  w += (size_t)M_TOT * NCONN * 2;
    __hip_bfloat16* fbuf = (__hip_bfloat16*)w;  w += (size_t)M_TOT * NL * 2;
    __hip_bfloat16* ubuf = (__hip_bfloat16*)w;  w += (size_t)M_TOT * NL * 2;
    __hip_bfloat16* xbuf = (__hip_bfloat16*)w;  w += (size_t)M_TOT * IN_DIM * 2;
    __hip_bfloat16* WfT  = (__hip_bfloat16*)w;  w += (size_t)NL * IN_DIM * 2;
    __hip_bfloat16* Bti  = (__hip_bfloat16*)w;  w += (size_t)NL * 1024 * 2;
    __hip_bfloat16* Btg  = (__hip_bfloat16*)w;  w += (size_t)NL * 1024 * 2;
    __hip_bfloat16* Btc  = (__hip_bfloat16*)w;  w += (size_t)NL * NCONN * 2;

    // prep
    wconv_transpose<<<32, 256, 0, stream>>>(Wf, WfT, 256, 512, 256, 0);
    wconv_transpose<<<64, 256, 0, stream>>>(Wi, Bti, 512, 512, 1024, 0);
    wconv_transpose<<<64, 256, 0, stream>>>(Ri, Bti, 512, 512, 1024, 512);
    wconv_transpose<<<64, 256, 0, stream>>>(Wg, Btg, 512, 512, 1024, 0);
    wconv_transpose<<<64, 256, 0, stream>>>(Rg, Btg, 512, 512, 1024, 512);
    wconv_transpose<<<32, 256, 0, stream>>>(Wc, Btc, 256, 512, 256, 0);
    conv_bf16_vec<<<(M_TOT * NCONN / 4 + 255) / 256, 256, 0, stream>>>(
        conn, cbuf, M_TOT * NCONN);
    xprep_transpose<<<NB * 32, 256, 0, stream>>>(x, xbuf);
    fill_init_h<<<1, 512, 0, stream>>>(init_h, abuf);

    // z = LN(cos(x^T Wf + bf)) -> abuf[:, 0:512] and shifted [:, 512:1024]
    k1_mfma_fourier_ln<<<M_TOT / 64, 512, 0, stream>>>(
        xbuf, WfT, bfv, gamma, beta, abuf);

    // u = conn @ Wc + bc -> ubuf (bf16)
    gemm_mfma<NCONN, false><<<dim3(M_TOT / 256, NL / 128), 512, 0, stream>>>(
        cbuf, Btc, nullptr, nullptr, nullptr, bc, nullptr, ubuf);

    // gates
    gemm_mfma<1024, true><<<dim3(M_TOT / 256, NL / 128), 512, 0, stream>>>(
        abuf, Bti, Btg, bi, bg, nullptr, fbuf, ubuf);

    k3_scan<<<NB * 8, 64, 0, stream>>>(abuf, fbuf, ubuf, init_c, (float*)d_out);
}

// Round 5
// 145.622 us; speedup vs baseline: 5.5057x; 1.0676x over previous
//
#include <hip/hip_runtime.h>
#include <hip/hip_bf16.h>

#define NB 32
#define IN_DIM 256
#define NT 512
#define NL 512
#define NCONN 256
#define LN_EPS 1e-3f
#define M_TOT (NB * NT)   // 16384 rows

typedef __attribute__((ext_vector_type(8))) short short8;
typedef __attribute__((ext_vector_type(4))) float f32x4;

__device__ __forceinline__ void async_copy16(void* lds_dst, const void* g_src) {
    __builtin_amdgcn_global_load_lds(
        (const __attribute__((address_space(1))) unsigned int*)g_src,
        (__attribute__((address_space(3))) unsigned int*)lds_dst, 16, 0, 0);
}

// ---------------------------------------------------------------------------
// x prep: Axt[b*512+t][k] = bf16(x[b][k][t])
// ---------------------------------------------------------------------------
__global__ __launch_bounds__(256) void xprep_transpose(
    const float* __restrict__ x, __hip_bfloat16* __restrict__ Axt)
{
    __shared__ float t[64][65];
    const int tilesPerB = (IN_DIM / 64) * (NT / 64);
    const int b  = blockIdx.x / tilesPerB;
    const int tl = blockIdx.x % tilesPerB;
    const int k0 = (tl / (NT / 64)) * 64;
    const int t0 = (tl % (NT / 64)) * 64;
    const int tid = threadIdx.x;
    const float* src = x + (size_t)b * IN_DIM * NT;
    for (int idx = tid; idx < 4096; idx += 256) {
        const int kk = idx >> 6, tt = idx & 63;
        t[kk][tt] = src[(size_t)(k0 + kk) * NT + t0 + tt];
    }
    __syncthreads();
    for (int idx = tid; idx < 4096; idx += 256) {
        const int tt = idx >> 6, kk = idx & 63;
        Axt[((size_t)b * NT + t0 + tt) * IN_DIM + k0 + kk] =
            __float2bfloat16(t[kk][tt]);
    }
}

__global__ void fill_init_h(const float* __restrict__ init_h,
                            __hip_bfloat16* __restrict__ abuf)
{
    const int l = threadIdx.x;
    const __hip_bfloat16 v = __float2bfloat16(init_h[l]);
    for (int b = 0; b < NB; b++)
        abuf[((size_t)b * NT) * 1024 + 512 + l] = v;
}

// ---------------------------------------------------------------------------
// Kernel 1 (MFMA 16x16x32): P = Axt @ WfT^T (64 rows x 512 cols per block),
// p = cos(P+bf), LN over cols, write abuf = [z | z_prev] bf16.
// ---------------------------------------------------------------------------
__global__ __launch_bounds__(512, 2) void k1_mfma_fourier_ln(
    const __hip_bfloat16* __restrict__ Axt,   // [M_TOT][256]
    const __hip_bfloat16* __restrict__ WfT,   // [512][256]
    const float* __restrict__ bf, const float* __restrict__ gamma,
    const float* __restrict__ beta,
    __hip_bfloat16* __restrict__ abuf)
{
    constexpr int ABYTES = 64 * 128;          // 8 KB
    constexpr int BBYTES = 512 * 128;         // 64 KB
    constexpr int NBUFB  = ABYTES + BBYTES;
    __shared__ __align__(16) char lds[2 * NBUFB];     // 144 KB
    __shared__ float pS[64][8], pQ[64][8];
    __shared__ float mS[64], rS[64];

    const int tid  = threadIdx.x;
    const int wave = tid >> 6, lane = tid & 63;
    const int m0 = blockIdx.x * 64;

    f32x4 acc[4][4];
#pragma unroll
    for (int mi = 0; mi < 4; mi++)
#pragma unroll
        for (int ni = 0; ni < 4; ni++) acc[mi][ni] = f32x4{0.f, 0.f, 0.f, 0.f};

    const int rowq = tid >> 3;
    const int sswz = ((tid & 7) ^ (rowq & 7)) << 4;
    const char* Ab = (const char*)Axt;
    const char* Bb = (const char*)WfT;

    auto stage = [&](int buf, int kt) {
        const size_t kb = (size_t)kt * 128;
        char* base = lds + buf * NBUFB;
        async_copy16(base + tid * 16,
                     Ab + (size_t)(m0 + rowq) * 512 + kb + sswz);
#pragma unroll
        for (int j = 0; j < 8; j++) {
            const int row = j * 64 + rowq;
            async_copy16(base + ABYTES + (j * 512 + tid) * 16,
                         Bb + (size_t)row * 512 + kb + sswz);
        }
    };

    // 16x16x32 fragment addressing (conflict-free, R2-verified)
    const int l15 = lane & 15, lq = lane >> 4, l7 = lane & 7;
    int kxB[2];
#pragma unroll
    for (int ks = 0; ks < 2; ks++) kxB[ks] = ((ks * 4 + lq) ^ l7) << 4;

    stage(0, 0);
    int cur = 0;
#pragma unroll 1
    for (int kt = 0; kt < 4; kt++) {
        __syncthreads();
        if (kt + 1 < 4) stage(cur ^ 1, kt + 1);
        const char* sA = lds + cur * NBUFB;
        const char* sB = sA + ABYTES;
#pragma unroll
        for (int ks = 0; ks < 2; ks++) {
            const int kx = kxB[ks];
            short8 a[4], b[4];
#pragma unroll
            for (int mi = 0; mi < 4; mi++)
                a[mi] = *(const short8*)(sA + (size_t)(mi * 16 + l15) * 128 + kx);
#pragma unroll
            for (int ni = 0; ni < 4; ni++)
                b[ni] = *(const short8*)(sB +
                    (size_t)(wave * 64 + ni * 16 + l15) * 128 + kx);
#pragma unroll
            for (int ni = 0; ni < 4; ni++)
#pragma unroll
                for (int mi = 0; mi < 4; mi++)
                    acc[mi][ni] = __builtin_amdgcn_mfma_f32_16x16x32_bf16(
                        a[mi], b[ni], acc[mi][ni], 0, 0, 0);
        }
        cur ^= 1;
    }

    // ---- LN epilogue (C/D: col = lane&15, row = mi*16 + lq*4 + r) ----
    int cg[4]; float bfc[4];
#pragma unroll
    for (int ni = 0; ni < 4; ni++) {
        cg[ni] = wave * 64 + ni * 16 + l15;
        bfc[ni] = bf[cg[ni]];
    }

#pragma unroll
    for (int mi = 0; mi < 4; mi++) {
#pragma unroll
        for (int r = 0; r < 4; r++) {
            float s = 0.f, q = 0.f;
#pragma unroll
            for (int ni = 0; ni < 4; ni++) {
                const float p = __cosf(acc[mi][ni][r] + bfc[ni]);
                s += p; q += p * p;
            }
#pragma unroll
            for (int off = 8; off >= 1; off >>= 1) {
                s += __shfl_xor(s, off);
                q += __shfl_xor(q, off);
            }
            if (l15 == 0) {
                const int row = mi * 16 + lq * 4 + r;
                pS[row][wave] = s;
                pQ[row][wave] = q;
            }
        }
    }
    __syncthreads();
    if (tid < 64) {
        float a = 0.f, qq = 0.f;
#pragma unroll
        for (int w = 0; w < 8; w++) { a += pS[tid][w]; qq += pQ[tid][w]; }
        const float mu = a * (1.0f / NL);
        const float var = qq * (1.0f / NL) - mu * mu;
        mS[tid] = mu;
        rS[tid] = rsqrtf(var + LN_EPS);
    }
    __syncthreads();

    float gm[4], bt[4];
#pragma unroll
    for (int ni = 0; ni < 4; ni++) { gm[ni] = gamma[cg[ni]]; bt[ni] = beta[cg[ni]]; }

#pragma unroll
    for (int mi = 0; mi < 4; mi++) {
#pragma unroll
        for (int r = 0; r < 4; r++) {
            const int row = mi * 16 + lq * 4 + r;
            const int m = m0 + row;
            const int t = m & (NT - 1);
            const float mu = mS[row], rs = rS[row];
#pragma unroll
            for (int ni = 0; ni < 4; ni++) {
                const float p = __cosf(acc[mi][ni][r] + bfc[ni]);
                const float z = gm[ni] * (p - mu) * rs + bt[ni];
                const __hip_bfloat16 zb = __float2bfloat16(z);
                abuf[(size_t)m * 1024 + cg[ni]] = zb;
                if (t != NT - 1) abuf[(size_t)(m + 1) * 1024 + 512 + cg[ni]] = zb;
            }
        }
    }
}

// ---------------------------------------------------------------------------
// Weight transpose+convert: dst[n][k_off+k] = bf16(src[k][n]); src is K x N.
// ---------------------------------------------------------------------------
__global__ __launch_bounds__(256) void wconv_transpose(
    const float* __restrict__ src, __hip_bfloat16* __restrict__ dst,
    int K, int N, int lddst, int k_off)
{
    __shared__ float t[64][65];
    const int ntn = N >> 6;
    const int k0 = (blockIdx.x / ntn) << 6;
    const int n0 = (blockIdx.x % ntn) << 6;
    const int tid = threadIdx.x;
    for (int idx = tid; idx < 4096; idx += 256) {
        const int kk = idx >> 6, nn = idx & 63;
        t[kk][nn] = src[(size_t)(k0 + kk) * N + n0 + nn];
    }
    __syncthreads();
    for (int idx = tid; idx < 4096; idx += 256) {
        const int nn = idx >> 6, kk = idx & 63;
        dst[(size_t)(n0 + nn) * lddst + k_off + k0 + kk] = __float2bfloat16(t[kk][nn]);
    }
}

__global__ __launch_bounds__(256) void conv_bf16_vec(
    const float* __restrict__ src, __hip_bfloat16* __restrict__ dst, int n)
{
    const int e = (blockIdx.x * 256 + threadIdx.x) * 4;
    if (e < n) {
        const float4 v = *(const float4*)(src + e);
        dst[e + 0] = __float2bfloat16(v.x);
        dst[e + 1] = __float2bfloat16(v.y);
        dst[e + 2] = __float2bfloat16(v.z);
        dst[e + 3] = __float2bfloat16(v.w);
    }
}

// ---------------------------------------------------------------------------
// MFMA GEMM: 256x128 tile, BK=64, 8 waves (4x2), 16x16x32 frags,
// wave tile 64x64 (dual-gate). Double-buffered stage-ahead.
// DUAL: f=sig(A@Bg^T+bg)->fb, iu=sig(A@Bi^T+bi)*u->ub.  !DUAL: ub=A@B0^T+bc.
// ---------------------------------------------------------------------------
template<int KTOT, bool DUAL>
__global__ __launch_bounds__(512, 2) void gemm_mfma(
    const __hip_bfloat16* __restrict__ A,
    const __hip_bfloat16* __restrict__ B0,
    const __hip_bfloat16* __restrict__ B1,
    const float* __restrict__ bi, const float* __restrict__ bg,
    const float* __restrict__ bc,
    __hip_bfloat16* __restrict__ fb, __hip_bfloat16* __restrict__ ub)
{
    constexpr int ABYTES = 256 * 128;
    constexpr int BBYTES = 128 * 128;
    constexpr int NBUFB  = ABYTES + (DUAL ? 2 : 1) * BBYTES;
    __shared__ __align__(16) char lds[2 * NBUFB];

    const int tid  = threadIdx.x;
    const int wave = tid >> 6, lane = tid & 63;
    const int wm = wave >> 1, wn = wave & 1;       // 4 x 2 wave grid
    const int m0 = blockIdx.x * 256;
    const int n0 = blockIdx.y * 128;

    f32x4 acc0[4][4];
    f32x4 acc1[DUAL ? 4 : 1][DUAL ? 4 : 1];
#pragma unroll
    for (int mi = 0; mi < 4; mi++)
#pragma unroll
        for (int ni = 0; ni < 4; ni++) {
            acc0[mi][ni] = f32x4{0.f, 0.f, 0.f, 0.f};
            if constexpr (DUAL) acc1[mi][ni] = f32x4{0.f, 0.f, 0.f, 0.f};
        }

    const int rowq = tid >> 3;
    const int sswz = (((tid & 7) ^ (rowq & 7)) << 4);
    const char* Ab  = (const char*)A;
    const char* B0b = (const char*)B0;
    const char* B1b = (const char*)B1;
    constexpr size_t ldk = (size_t)KTOT * 2;

    auto stage = [&](int buf, int kt) {
        const size_t kb = (size_t)kt * 128;
        char* base = lds + buf * NBUFB;
#pragma unroll
        for (int j = 0; j < 4; j++) {
            const int row = j * 64 + rowq;
            async_copy16(base + (j * 512 + tid) * 16,
                         Ab + (size_t)(m0 + row) * ldk + kb + sswz);
        }
#pragma unroll
        for (int j = 0; j < 2; j++) {
            const int row = j * 64 + rowq;
            async_copy16(base + ABYTES + (j * 512 + tid) * 16,
                         B0b + (size_t)(n0 + row) * ldk + kb + sswz);
            if constexpr (DUAL)
                async_copy16(base + ABYTES + BBYTES + (j * 512 + tid) * 16,
                             B1b + (size_t)(n0 + row) * ldk + kb + sswz);
        }
    };

    // 16x16x32 fragment addressing (conflict-free)
    const int l15 = lane & 15, lq = lane >> 4, l7 = lane & 7;
    int kxB[2];
#pragma unroll
    for (int ks = 0; ks < 2; ks++) kxB[ks] = ((ks * 4 + lq) ^ l7) << 4;

    constexpr int KSTEPS = KTOT / 64;
    stage(0, 0);
    int cur = 0;
#pragma unroll 1
    for (int kt = 0; kt < KSTEPS; kt++) {
        __syncthreads();
        if (kt + 1 < KSTEPS) stage(cur ^ 1, kt + 1);
        const char* sA  = lds + cur * NBUFB;
        const char* sB0 = sA + ABYTES;
        const char* sB1 = sB0 + BBYTES;
#pragma unroll
        for (int ks = 0; ks < 2; ks++) {
            const int kx = kxB[ks];
            short8 a[4], b0[4];
#pragma unroll
            for (int mi = 0; mi < 4; mi++)
                a[mi] = *(const short8*)(sA +
                    (size_t)(wm * 64 + mi * 16 + l15) * 128 + kx);
#pragma unroll
            for (int ni = 0; ni < 4; ni++)
                b0[ni] = *(const short8*)(sB0 +
                    (size_t)(wn * 64 + ni * 16 + l15) * 128 + kx);
#pragma unroll
            for (int ni = 0; ni < 4; ni++)
#pragma unroll
                for (int mi = 0; mi < 4; mi++)
                    acc0[mi][ni] = __builtin_amdgcn_mfma_f32_16x16x32_bf16(
                        a[mi], b0[ni], acc0[mi][ni], 0, 0, 0);
            if constexpr (DUAL) {
                short8 b1[4];
#pragma unroll
                for (int ni = 0; ni < 4; ni++)
                    b1[ni] = *(const short8*)(sB1 +
                        (size_t)(wn * 64 + ni * 16 + l15) * 128 + kx);
#pragma unroll
                for (int ni = 0; ni < 4; ni++)
#pragma unroll
                    for (int mi = 0; mi < 4; mi++)
                        acc1[mi][ni] = __builtin_amdgcn_mfma_f32_16x16x32_bf16(
                            a[mi], b1[ni], acc1[mi][ni], 0, 0, 0);
            }
        }
        cur ^= 1;
    }

    // epilogue: C/D col = lane&15, row = mi*16 + lq*4 + r
#pragma unroll
    for (int ni = 0; ni < 4; ni++) {
        const int l = n0 + wn * 64 + ni * 16 + l15;
        float bil = 0.f, bgl = 0.f, bcl = 0.f;
        if constexpr (DUAL) { bil = bi[l]; bgl = bg[l]; }
        else                { bcl = bc[l]; }
#pragma unroll
        for (int mi = 0; mi < 4; mi++) {
#pragma unroll
            for (int r = 0; r < 4; r++) {
                const int m = m0 + wm * 64 + mi * 16 + lq * 4 + r;
                const size_t idx = (size_t)m * NL + l;
                if constexpr (DUAL) {
                    const float ipre = acc0[mi][ni][r] + bil;
                    const float fpre = acc1[mi][ni][r] + bgl;
                    const float fv = 1.f / (1.f + __expf(-fpre));
                    const float iv = 1.f / (1.f + __expf(-ipre));
                    const float uv = __bfloat162float(ub[idx]);
                    fb[idx] = __float2bfloat16(fv);
                    ub[idx] = __float2bfloat16(iv * uv);
                } else {
                    ub[idx] = __float2bfloat16(acc0[mi][ni][r] + bcl);
                }
            }
        }
    }
}

// ---------------------------------------------------------------------------
// Kernel 3: sequential scan; h = sin(z)*c; out[b,l,t].
// ---------------------------------------------------------------------------
__global__ __launch_bounds__(64) void k3_scan(
    const __hip_bfloat16* __restrict__ zab,
    const __hip_bfloat16* __restrict__ fb,
    const __hip_bfloat16* __restrict__ ub,
    const float* __restrict__ init_c, float* __restrict__ out)
{
    const int b = blockIdx.x >> 3;
    const int l = ((blockIdx.x & 7) << 6) + threadIdx.x;
    float c = init_c[l];

    const __hip_bfloat16* zp = zab + (size_t)b * NT * 1024 + l;
    const __hip_bfloat16* fp = fb  + (size_t)b * NT * NL + l;
    const __hip_bfloat16* ip = ub  + (size_t)b * NT * NL + l;
    float* op = out + ((size_t)b * NL + l) * NT;

    for (int t0 = 0; t0 < NT; t0 += 16) {
        float fv[16], iv[16], zv[16];
#pragma unroll
        for (int j = 0; j < 16; j++) {
            fv[j] = __bfloat162float(fp[(size_t)(t0 + j) * NL]);
            iv[j] = __bfloat162float(ip[(size_t)(t0 + j) * NL]);
            zv[j] = __bfloat162float(zp[(size_t)(t0 + j) * 1024]);
        }
        float h[16];
#pragma unroll
        for (int j = 0; j < 16; j++) {
            c = fv[j] * c + iv[j];
            h[j] = __sinf(zv[j]) * c;
        }
        float4* o4 = (float4*)(op + t0);
        o4[0] = make_float4(h[0],  h[1],  h[2],  h[3]);
        o4[1] = make_float4(h[4],  h[5],  h[6],  h[7]);
        o4[2] = make_float4(h[8],  h[9],  h[10], h[11]);
        o4[3] = make_float4(h[12], h[13], h[14], h[15]);
    }
}

// ---------------------------------------------------------------------------
extern "C" void kernel_launch(void* const* d_in, const int* in_sizes, int n_in,
                              void* d_out, int out_size, void* d_ws, size_t ws_size,
                              hipStream_t stream)
{
    const float* x      = (const float*)d_in[0];
    const float* conn   = (const float*)d_in[1];
    const float* Wf     = (const float*)d_in[2];
    const float* bfv    = (const float*)d_in[3];
    const float* gamma  = (const float*)d_in[4];
    const float* beta   = (const float*)d_in[5];
    const float* Wi     = (const float*)d_in[6];
    const float* Ri     = (const float*)d_in[7];
    const float* bi     = (const float*)d_in[8];
    const float* Wg     = (const float*)d_in[9];
    const float* Rg     = (const float*)d_in[10];
    const float* bg     = (const float*)d_in[11];
    const float* Wc     = (const float*)d_in[12];
    const float* bc     = (const float*)d_in[13];
    const float* init_h = (const float*)d_in[14];
    const float* init_c = (const float*)d_in[15];

    char* w = (char*)d_ws;
    __hip_bfloat16* abuf = (__hip_bfloat16*)w;  w += (size_t)M_TOT * 1024 * 2;
    __hip_bfloat16* cbuf = (__hip_bfloat16*)w;  w += (size_t)M_TOT * NCONN * 2;
    __hip_bfloat16* fbuf = (__hip_bfloat16*)w;  w += (size_t)M_TOT * NL * 2;
    __hip_bfloat16* ubuf = (__hip_bfloat16*)w;  w += (size_t)M_TOT * NL * 2;
    __hip_bfloat16* xbuf = (__hip_bfloat16*)w;  w += (size_t)M_TOT * IN_DIM * 2;
    __hip_bfloat16* WfT  = (__hip_bfloat16*)w;  w += (size_t)NL * IN_DIM * 2;
    __hip_bfloat16* Bti  = (__hip_bfloat16*)w;  w += (size_t)NL * 1024 * 2;
    __hip_bfloat16* Btg  = (__hip_bfloat16*)w;  w += (size_t)NL * 1024 * 2;
    __hip_bfloat16* Btc  = (__hip_bfloat16*)w;  w += (size_t)NL * NCONN * 2;

    // prep
    wconv_transpose<<<32, 256, 0, stream>>>(Wf, WfT, 256, 512, 256, 0);
    wconv_transpose<<<64, 256, 0, stream>>>(Wi, Bti, 512, 512, 1024, 0);
    wconv_transpose<<<64, 256, 0, stream>>>(Ri, Bti, 512, 512, 1024, 512);
    wconv_transpose<<<64, 256, 0, stream>>>(Wg, Btg, 512, 512, 1024, 0);
    wconv_transpose<<<64, 256, 0, stream>>>(Rg, Btg, 512, 512, 1024, 512);
    wconv_transpose<<<32, 256, 0, stream>>>(Wc, Btc, 256, 512, 256, 0);
    conv_bf16_vec<<<(M_TOT * NCONN / 4 + 255) / 256, 256, 0, stream>>>(
        conn, cbuf, M_TOT * NCONN);
    xprep_transpose<<<NB * 32, 256, 0, stream>>>(x, xbuf);
    fill_init_h<<<1, 512, 0, stream>>>(init_h, abuf);

    // z = LN(cos(x^T Wf + bf)) -> abuf[:, 0:512] and shifted [:, 512:1024]
    k1_mfma_fourier_ln<<<M_TOT / 64, 512, 0, stream>>>(
        xbuf, WfT, bfv, gamma, beta, abuf);

    // u = conn @ Wc + bc -> ubuf (bf16)
    gemm_mfma<NCONN, false><<<dim3(M_TOT / 256, NL / 128), 512, 0, stream>>>(
        cbuf, Btc, nullptr, nullptr, nullptr, bc, nullptr, ubuf);

    // gates
    gemm_mfma<1024, true><<<dim3(M_TOT / 256, NL / 128), 512, 0, stream>>>(
        abuf, Bti, Btg, bi, bg, nullptr, fbuf, ubuf);

    k3_scan<<<NB * 8, 64, 0, stream>>>(abuf, fbuf, ubuf, init_c, (float*)d_out);
}

// Round 6
// 142.775 us; speedup vs baseline: 5.6155x; 1.0199x over previous
//
#include <hip/hip_runtime.h>
#include <hip/hip_bf16.h>

#define NB 32
#define IN_DIM 256
#define NT 512
#define NL 512
#define NCONN 256
#define LN_EPS 1e-3f
#define M_TOT (NB * NT)   // 16384 rows

typedef __attribute__((ext_vector_type(8))) short short8;
typedef __attribute__((ext_vector_type(4))) float f32x4;

__device__ __forceinline__ void async_copy16(void* lds_dst, const void* g_src) {
    __builtin_amdgcn_global_load_lds(
        (const __attribute__((address_space(1))) unsigned int*)g_src,
        (__attribute__((address_space(3))) unsigned int*)lds_dst, 16, 0, 0);
}

// ---------------------------------------------------------------------------
// x prep: Axt[b*512+t][k] = bf16(x[b][k][t])
// ---------------------------------------------------------------------------
__global__ __launch_bounds__(256) void xprep_transpose(
    const float* __restrict__ x, __hip_bfloat16* __restrict__ Axt)
{
    __shared__ float t[64][65];
    const int tilesPerB = (IN_DIM / 64) * (NT / 64);
    const int b  = blockIdx.x / tilesPerB;
    const int tl = blockIdx.x % tilesPerB;
    const int k0 = (tl / (NT / 64)) * 64;
    const int t0 = (tl % (NT / 64)) * 64;
    const int tid = threadIdx.x;
    const float* src = x + (size_t)b * IN_DIM * NT;
    for (int idx = tid; idx < 4096; idx += 256) {
        const int kk = idx >> 6, tt = idx & 63;
        t[kk][tt] = src[(size_t)(k0 + kk) * NT + t0 + tt];
    }
    __syncthreads();
    for (int idx = tid; idx < 4096; idx += 256) {
        const int tt = idx >> 6, kk = idx & 63;
        Axt[((size_t)b * NT + t0 + tt) * IN_DIM + k0 + kk] =
            __float2bfloat16(t[kk][tt]);
    }
}

__global__ void fill_init_h(const float* __restrict__ init_h,
                            __hip_bfloat16* __restrict__ abuf)
{
    const int l = threadIdx.x;
    const __hip_bfloat16 v = __float2bfloat16(init_h[l]);
    for (int b = 0; b < NB; b++)
        abuf[((size_t)b * NT) * 1024 + 512 + l] = v;
}

// ---------------------------------------------------------------------------
// Kernel 1 (MFMA 16x16x32): P = Axt @ WfT^T (64 rows x 512 cols per block),
// p = cos(P+bf), LN over cols, write abuf = [z | z_prev] bf16.  (unchanged)
// ---------------------------------------------------------------------------
__global__ __launch_bounds__(512, 2) void k1_mfma_fourier_ln(
    const __hip_bfloat16* __restrict__ Axt,   // [M_TOT][256]
    const __hip_bfloat16* __restrict__ WfT,   // [512][256]
    const float* __restrict__ bf, const float* __restrict__ gamma,
    const float* __restrict__ beta,
    __hip_bfloat16* __restrict__ abuf)
{
    constexpr int ABYTES = 64 * 128;          // 8 KB
    constexpr int BBYTES = 512 * 128;         // 64 KB
    constexpr int NBUFB  = ABYTES + BBYTES;
    __shared__ __align__(16) char lds[2 * NBUFB];     // 144 KB
    __shared__ float pS[64][8], pQ[64][8];
    __shared__ float mS[64], rS[64];

    const int tid  = threadIdx.x;
    const int wave = tid >> 6, lane = tid & 63;
    const int m0 = blockIdx.x * 64;

    f32x4 acc[4][4];
#pragma unroll
    for (int mi = 0; mi < 4; mi++)
#pragma unroll
        for (int ni = 0; ni < 4; ni++) acc[mi][ni] = f32x4{0.f, 0.f, 0.f, 0.f};

    const int rowq = tid >> 3;
    const int sswz = ((tid & 7) ^ (rowq & 7)) << 4;
    const char* Ab = (const char*)Axt;
    const char* Bb = (const char*)WfT;

    auto stage = [&](int buf, int kt) {
        const size_t kb = (size_t)kt * 128;
        char* base = lds + buf * NBUFB;
        async_copy16(base + tid * 16,
                     Ab + (size_t)(m0 + rowq) * 512 + kb + sswz);
#pragma unroll
        for (int j = 0; j < 8; j++) {
            const int row = j * 64 + rowq;
            async_copy16(base + ABYTES + (j * 512 + tid) * 16,
                         Bb + (size_t)row * 512 + kb + sswz);
        }
    };

    const int l15 = lane & 15, lq = lane >> 4, l7 = lane & 7;
    int kxB[2];
#pragma unroll
    for (int ks = 0; ks < 2; ks++) kxB[ks] = ((ks * 4 + lq) ^ l7) << 4;

    stage(0, 0);
    int cur = 0;
#pragma unroll 1
    for (int kt = 0; kt < 4; kt++) {
        __syncthreads();
        if (kt + 1 < 4) stage(cur ^ 1, kt + 1);
        const char* sA = lds + cur * NBUFB;
        const char* sB = sA + ABYTES;
#pragma unroll
        for (int ks = 0; ks < 2; ks++) {
            const int kx = kxB[ks];
            short8 a[4], b[4];
#pragma unroll
            for (int mi = 0; mi < 4; mi++)
                a[mi] = *(const short8*)(sA + (size_t)(mi * 16 + l15) * 128 + kx);
#pragma unroll
            for (int ni = 0; ni < 4; ni++)
                b[ni] = *(const short8*)(sB +
                    (size_t)(wave * 64 + ni * 16 + l15) * 128 + kx);
#pragma unroll
            for (int ni = 0; ni < 4; ni++)
#pragma unroll
                for (int mi = 0; mi < 4; mi++)
                    acc[mi][ni] = __builtin_amdgcn_mfma_f32_16x16x32_bf16(
                        a[mi], b[ni], acc[mi][ni], 0, 0, 0);
        }
        cur ^= 1;
    }

    int cg[4]; float bfc[4];
#pragma unroll
    for (int ni = 0; ni < 4; ni++) {
        cg[ni] = wave * 64 + ni * 16 + l15;
        bfc[ni] = bf[cg[ni]];
    }

#pragma unroll
    for (int mi = 0; mi < 4; mi++) {
#pragma unroll
        for (int r = 0; r < 4; r++) {
            float s = 0.f, q = 0.f;
#pragma unroll
            for (int ni = 0; ni < 4; ni++) {
                const float p = __cosf(acc[mi][ni][r] + bfc[ni]);
                s += p; q += p * p;
            }
#pragma unroll
            for (int off = 8; off >= 1; off >>= 1) {
                s += __shfl_xor(s, off);
                q += __shfl_xor(q, off);
            }
            if (l15 == 0) {
                const int row = mi * 16 + lq * 4 + r;
                pS[row][wave] = s;
                pQ[row][wave] = q;
            }
        }
    }
    __syncthreads();
    if (tid < 64) {
        float a = 0.f, qq = 0.f;
#pragma unroll
        for (int w = 0; w < 8; w++) { a += pS[tid][w]; qq += pQ[tid][w]; }
        const float mu = a * (1.0f / NL);
        const float var = qq * (1.0f / NL) - mu * mu;
        mS[tid] = mu;
        rS[tid] = rsqrtf(var + LN_EPS);
    }
    __syncthreads();

    float gm[4], bt[4];
#pragma unroll
    for (int ni = 0; ni < 4; ni++) { gm[ni] = gamma[cg[ni]]; bt[ni] = beta[cg[ni]]; }

#pragma unroll
    for (int mi = 0; mi < 4; mi++) {
#pragma unroll
        for (int r = 0; r < 4; r++) {
            const int row = mi * 16 + lq * 4 + r;
            const int m = m0 + row;
            const int t = m & (NT - 1);
            const float mu = mS[row], rs = rS[row];
#pragma unroll
            for (int ni = 0; ni < 4; ni++) {
                const float p = __cosf(acc[mi][ni][r] + bfc[ni]);
                const float z = gm[ni] * (p - mu) * rs + bt[ni];
                const __hip_bfloat16 zb = __float2bfloat16(z);
                abuf[(size_t)m * 1024 + cg[ni]] = zb;
                if (t != NT - 1) abuf[(size_t)(m + 1) * 1024 + 512 + cg[ni]] = zb;
            }
        }
    }
}

// ---------------------------------------------------------------------------
// Weight transpose+convert / conn convert (unchanged)
// ---------------------------------------------------------------------------
__global__ __launch_bounds__(256) void wconv_transpose(
    const float* __restrict__ src, __hip_bfloat16* __restrict__ dst,
    int K, int N, int lddst, int k_off)
{
    __shared__ float t[64][65];
    const int ntn = N >> 6;
    const int k0 = (blockIdx.x / ntn) << 6;
    const int n0 = (blockIdx.x % ntn) << 6;
    const int tid = threadIdx.x;
    for (int idx = tid; idx < 4096; idx += 256) {
        const int kk = idx >> 6, nn = idx & 63;
        t[kk][nn] = src[(size_t)(k0 + kk) * N + n0 + nn];
    }
    __syncthreads();
    for (int idx = tid; idx < 4096; idx += 256) {
        const int nn = idx >> 6, kk = idx & 63;
        dst[(size_t)(n0 + nn) * lddst + k_off + k0 + kk] = __float2bfloat16(t[kk][nn]);
    }
}

__global__ __launch_bounds__(256) void conv_bf16_vec(
    const float* __restrict__ src, __hip_bfloat16* __restrict__ dst, int n)
{
    const int e = (blockIdx.x * 256 + threadIdx.x) * 4;
    if (e < n) {
        const float4 v = *(const float4*)(src + e);
        dst[e + 0] = __float2bfloat16(v.x);
        dst[e + 1] = __float2bfloat16(v.y);
        dst[e + 2] = __float2bfloat16(v.z);
        dst[e + 3] = __float2bfloat16(v.w);
    }
}

// ---------------------------------------------------------------------------
// Deep-pipelined MFMA GEMM: 256x128 tile, 8 waves, 16x16x32 frags.
// K split into 32-wide halves; 4 rotating LDS slots; 3 halves in flight with
// counted vmcnt + raw s_barrier (T3+T4). XCD-swizzled blockIdx.
// Half-tile LDS: 64B rows, slot swizzle phys = lq ^ ((row>>1)&3) (bank-free).
// DUAL: f=sig(A@Bg^T+bg)->fb, iu=sig(A@Bi^T+bi)*u->ub.  !DUAL: ub=A@B0^T+bc.
// ---------------------------------------------------------------------------
template<int KTOT, bool DUAL>
__global__ __launch_bounds__(512, 2) void gemm_pipe(
    const __hip_bfloat16* __restrict__ A,
    const __hip_bfloat16* __restrict__ B0,
    const __hip_bfloat16* __restrict__ B1,
    const float* __restrict__ bi, const float* __restrict__ bg,
    const float* __restrict__ bc,
    __hip_bfloat16* __restrict__ fb, __hip_bfloat16* __restrict__ ub)
{
    constexpr int H = KTOT / 32;              // total half-tiles
    constexpr int A_SLOT = 256 * 32 * 2;      // 16 KB
    constexpr int B_SLOT = 128 * 32 * 2;      // 8 KB
    constexpr int A_TOT  = 4 * A_SLOT;        // 64 KB
    constexpr int B_TOT  = 4 * B_SLOT;        // 32 KB
    __shared__ __align__(16) char lds[A_TOT + (DUAL ? 2 : 1) * B_TOT];

    const int tid  = threadIdx.x;
    const int wave = tid >> 6, lane = tid & 63;
    const int wm = wave >> 1, wn = wave & 1;
    // XCD-aware swizzle: 256 blocks, 8 XCDs, 32 consecutive logical per XCD
    const int d = blockIdx.x;
    const int L = ((d & 7) << 5) | (d >> 3);
    const int m0 = (L >> 2) << 8;             // M-tile (64 of them)
    const int n0 = (L & 3) << 7;              // N-tile (4 of them)

    f32x4 acc0[4][4];
    f32x4 acc1[DUAL ? 4 : 1][DUAL ? 4 : 1];
#pragma unroll
    for (int mi = 0; mi < 4; mi++)
#pragma unroll
        for (int ni = 0; ni < 4; ni++) {
            acc0[mi][ni] = f32x4{0.f, 0.f, 0.f, 0.f};
            if constexpr (DUAL) acc1[mi][ni] = f32x4{0.f, 0.f, 0.f, 0.f};
        }

    const char* Ab  = (const char*)A;
    const char* B0b = (const char*)B0;
    const char* B1b = (const char*)B1;
    constexpr size_t ldk = (size_t)KTOT * 2;

    // staging lane constants
    const int rA0 = tid >> 2;                       // row within 128-row round
    const int slotT = tid & 3;
    // frag-read lane constants
    const int l15 = lane & 15, lq = lane >> 4;
    const int pb = ((lq ^ ((l15 >> 1) & 3)) << 4);  // phys byte within 64B row
    int aOff[4], bOff[4];
#pragma unroll
    for (int mi = 0; mi < 4; mi++) aOff[mi] = (wm * 64 + mi * 16 + l15) * 64 + pb;
#pragma unroll
    for (int ni = 0; ni < 4; ni++) bOff[ni] = (wn * 64 + ni * 16 + l15) * 64 + pb;

    auto stageHalf = [&](int h) {
        const int slot = h & 3;
        const size_t kb = (size_t)h * 64;           // byte offset along K
        char* aBase  = lds + slot * A_SLOT;
        char* b0Base = lds + A_TOT + slot * B_SLOT;
#pragma unroll
        for (int j = 0; j < 2; j++) {               // A: 2 x 128 rows
            const int r = j * 128 + rA0;
            const int lsl = slotT ^ ((r >> 1) & 3);
            async_copy16(aBase + j * 8192 + tid * 16,
                         Ab + (size_t)(m0 + r) * ldk + kb + lsl * 16);
        }
        const int rB = rA0;                          // B: 128 rows
        const int lslB = slotT ^ ((rB >> 1) & 3);
        async_copy16(b0Base + tid * 16,
                     B0b + (size_t)(n0 + rB) * ldk + kb + lslB * 16);
        if constexpr (DUAL)
            async_copy16(b0Base + B_TOT + tid * 16,
                         B1b + (size_t)(n0 + rB) * ldk + kb + lslB * 16);
    };

    auto computeHalf = [&](int h) {
        const char* sA  = lds + (h & 3) * A_SLOT;
        const char* sB0 = lds + A_TOT + (h & 3) * B_SLOT;
        short8 a[4], b0[4];
#pragma unroll
        for (int mi = 0; mi < 4; mi++)
            a[mi] = *(const short8*)(sA + aOff[mi]);
#pragma unroll
        for (int ni = 0; ni < 4; ni++)
            b0[ni] = *(const short8*)(sB0 + bOff[ni]);
#pragma unroll
        for (int ni = 0; ni < 4; ni++)
#pragma unroll
            for (int mi = 0; mi < 4; mi++)
                acc0[mi][ni] = __builtin_amdgcn_mfma_f32_16x16x32_bf16(
                    a[mi], b0[ni], acc0[mi][ni], 0, 0, 0);
        if constexpr (DUAL) {
            const char* sB1 = sB0 + B_TOT;
            short8 b1[4];
#pragma unroll
            for (int ni = 0; ni < 4; ni++)
                b1[ni] = *(const short8*)(sB1 + bOff[ni]);
#pragma unroll
            for (int ni = 0; ni < 4; ni++)
#pragma unroll
                for (int mi = 0; mi < 4; mi++)
                    acc1[mi][ni] = __builtin_amdgcn_mfma_f32_16x16x32_bf16(
                        a[mi], b1[ni], acc1[mi][ni], 0, 0, 0);
        }
    };

    // prologue: 3 halves in flight
    stageHalf(0); stageHalf(1); stageHalf(2);

#pragma unroll 4
    for (int h = 0; h < H - 2; h++) {
        if constexpr (DUAL) asm volatile("s_waitcnt vmcnt(8)" ::: "memory");
        else                asm volatile("s_waitcnt vmcnt(6)" ::: "memory");
        __builtin_amdgcn_s_barrier();
        __builtin_amdgcn_sched_barrier(0);
        if (h + 3 < H) stageHalf(h + 3);
        computeHalf(h);
    }
    // h = H-2
    if constexpr (DUAL) asm volatile("s_waitcnt vmcnt(4)" ::: "memory");
    else                asm volatile("s_waitcnt vmcnt(3)" ::: "memory");
    __builtin_amdgcn_s_barrier();
    __builtin_amdgcn_sched_barrier(0);
    computeHalf(H - 2);
    // h = H-1
    asm volatile("s_waitcnt vmcnt(0)" ::: "memory");
    __builtin_amdgcn_s_barrier();
    __builtin_amdgcn_sched_barrier(0);
    computeHalf(H - 1);

    // epilogue: C/D col = lane&15, row = mi*16 + lq*4 + r
#pragma unroll
    for (int ni = 0; ni < 4; ni++) {
        const int l = n0 + wn * 64 + ni * 16 + l15;
        float bil = 0.f, bgl = 0.f, bcl = 0.f;
        if constexpr (DUAL) { bil = bi[l]; bgl = bg[l]; }
        else                { bcl = bc[l]; }
#pragma unroll
        for (int mi = 0; mi < 4; mi++) {
#pragma unroll
            for (int r = 0; r < 4; r++) {
                const int m = m0 + wm * 64 + mi * 16 + lq * 4 + r;
                const size_t idx = (size_t)m * NL + l;
                if constexpr (DUAL) {
                    const float ipre = acc0[mi][ni][r] + bil;
                    const float fpre = acc1[mi][ni][r] + bgl;
                    const float fv = 1.f / (1.f + __expf(-fpre));
                    const float iv = 1.f / (1.f + __expf(-ipre));
                    const float uv = __bfloat162float(ub[idx]);
                    fb[idx] = __float2bfloat16(fv);
                    ub[idx] = __float2bfloat16(iv * uv);
                } else {
                    ub[idx] = __float2bfloat16(acc0[mi][ni][r] + bcl);
                }
            }
        }
    }
}

// ---------------------------------------------------------------------------
// Kernel 3: sequential scan; h = sin(z)*c; out[b,l,t].
// ---------------------------------------------------------------------------
__global__ __launch_bounds__(64) void k3_scan(
    const __hip_bfloat16* __restrict__ zab,
    const __hip_bfloat16* __restrict__ fb,
    const __hip_bfloat16* __restrict__ ub,
    const float* __restrict__ init_c, float* __restrict__ out)
{
    const int b = blockIdx.x >> 3;
    const int l = ((blockIdx.x & 7) << 6) + threadIdx.x;
    float c = init_c[l];

    const __hip_bfloat16* zp = zab + (size_t)b * NT * 1024 + l;
    const __hip_bfloat16* fp = fb  + (size_t)b * NT * NL + l;
    const __hip_bfloat16* ip = ub  + (size_t)b * NT * NL + l;
    float* op = out + ((size_t)b * NL + l) * NT;

    for (int t0 = 0; t0 < NT; t0 += 16) {
        float fv[16], iv[16], zv[16];
#pragma unroll
        for (int j = 0; j < 16; j++) {
            fv[j] = __bfloat162float(fp[(size_t)(t0 + j) * NL]);
            iv[j] = __bfloat162float(ip[(size_t)(t0 + j) * NL]);
            zv[j] = __bfloat162float(zp[(size_t)(t0 + j) * 1024]);
        }
        float h[16];
#pragma unroll
        for (int j = 0; j < 16; j++) {
            c = fv[j] * c + iv[j];
            h[j] = __sinf(zv[j]) * c;
        }
        float4* o4 = (float4*)(op + t0);
        o4[0] = make_float4(h[0],  h[1],  h[2],  h[3]);
        o4[1] = make_float4(h[4],  h[5],  h[6],  h[7]);
        o4[2] = make_float4(h[8],  h[9],  h[10], h[11]);
        o4[3] = make_float4(h[12], h[13], h[14], h[15]);
    }
}

// ---------------------------------------------------------------------------
extern "C" void kernel_launch(void* const* d_in, const int* in_sizes, int n_in,
                              void* d_out, int out_size, void* d_ws, size_t ws_size,
                              hipStream_t stream)
{
    const float* x      = (const float*)d_in[0];
    const float* conn   = (const float*)d_in[1];
    const float* Wf     = (const float*)d_in[2];
    const float* bfv    = (const float*)d_in[3];
    const float* gamma  = (const float*)d_in[4];
    const float* beta   = (const float*)d_in[5];
    const float* Wi     = (const float*)d_in[6];
    const float* Ri     = (const float*)d_in[7];
    const float* bi     = (const float*)d_in[8];
    const float* Wg     = (const float*)d_in[9];
    const float* Rg     = (const float*)d_in[10];
    const float* bg     = (const float*)d_in[11];
    const float* Wc     = (const float*)d_in[12];
    const float* bc     = (const float*)d_in[13];
    const float* init_h = (const float*)d_in[14];
    const float* init_c = (const float*)d_in[15];

    char* w = (char*)d_ws;
    __hip_bfloat16* abuf = (__hip_bfloat16*)w;  w += (size_t)M_TOT * 1024 * 2;
    __hip_bfloat16* cbuf = (__hip_bfloat16*)w;  w += (size_t)M_TOT * NCONN * 2;
    __hip_bfloat16* fbuf = (__hip_bfloat16*)w;  w += (size_t)M_TOT * NL * 2;
    __hip_bfloat16* ubuf = (__hip_bfloat16*)w;  w += (size_t)M_TOT * NL * 2;
    __hip_bfloat16* xbuf = (__hip_bfloat16*)w;  w += (size_t)M_TOT * IN_DIM * 2;
    __hip_bfloat16* WfT  = (__hip_bfloat16*)w;  w += (size_t)NL * IN_DIM * 2;
    __hip_bfloat16* Bti  = (__hip_bfloat16*)w;  w += (size_t)NL * 1024 * 2;
    __hip_bfloat16* Btg  = (__hip_bfloat16*)w;  w += (size_t)NL * 1024 * 2;
    __hip_bfloat16* Btc  = (__hip_bfloat16*)w;  w += (size_t)NL * NCONN * 2;

    // prep
    wconv_transpose<<<32, 256, 0, stream>>>(Wf, WfT, 256, 512, 256, 0);
    wconv_transpose<<<64, 256, 0, stream>>>(Wi, Bti, 512, 512, 1024, 0);
    wconv_transpose<<<64, 256, 0, stream>>>(Ri, Bti, 512, 512, 1024, 512);
    wconv_transpose<<<64, 256, 0, stream>>>(Wg, Btg, 512, 512, 1024, 0);
    wconv_transpose<<<64, 256, 0, stream>>>(Rg, Btg, 512, 512, 1024, 512);
    wconv_transpose<<<32, 256, 0, stream>>>(Wc, Btc, 256, 512, 256, 0);
    conv_bf16_vec<<<(M_TOT * NCONN / 4 + 255) / 256, 256, 0, stream>>>(
        conn, cbuf, M_TOT * NCONN);
    xprep_transpose<<<NB * 32, 256, 0, stream>>>(x, xbuf);
    fill_init_h<<<1, 512, 0, stream>>>(init_h, abuf);

    // z = LN(cos(x^T Wf + bf)) -> abuf[:, 0:512] and shifted [:, 512:1024]
    k1_mfma_fourier_ln<<<M_TOT / 64, 512, 0, stream>>>(
        xbuf, WfT, bfv, gamma, beta, abuf);

    // u = conn @ Wc + bc -> ubuf (bf16)
    gemm_pipe<NCONN, false><<<256, 512, 0, stream>>>(
        cbuf, Btc, nullptr, nullptr, nullptr, bc, nullptr, ubuf);

    // gates: fbuf = f, ubuf = i*u
    gemm_pipe<1024, true><<<256, 512, 0, stream>>>(
        abuf, Bti, Btg, bi, bg, nullptr, fbuf, ubuf);

    k3_scan<<<NB * 8, 64, 0, stream>>>(abuf, fbuf, ubuf, init_c, (float*)d_out);
}

// Round 8
// 135.341 us; speedup vs baseline: 5.9240x; 1.0549x over previous
//
#include <hip/hip_runtime.h>
#include <hip/hip_bf16.h>

#define NB 32
#define IN_DIM 256
#define NT 512
#define NL 512
#define NCONN 256
#define LN_EPS 1e-3f
#define M_TOT (NB * NT)   // 16384 rows

typedef __attribute__((ext_vector_type(8))) short short8;
typedef __attribute__((ext_vector_type(4))) float f32x4;

__device__ __forceinline__ void async_copy16(void* lds_dst, const void* g_src) {
    __builtin_amdgcn_global_load_lds(
        (const __attribute__((address_space(1))) unsigned int*)g_src,
        (__attribute__((address_space(3))) unsigned int*)lds_dst, 16, 0, 0);
}

// ---------------------------------------------------------------------------
// x prep: Axt[b*512+t][k] = bf16(x[b][k][t])
// ---------------------------------------------------------------------------
__global__ __launch_bounds__(256) void xprep_transpose(
    const float* __restrict__ x, __hip_bfloat16* __restrict__ Axt)
{
    __shared__ float t[64][65];
    const int tilesPerB = (IN_DIM / 64) * (NT / 64);
    const int b  = blockIdx.x / tilesPerB;
    const int tl = blockIdx.x % tilesPerB;
    const int k0 = (tl / (NT / 64)) * 64;
    const int t0 = (tl % (NT / 64)) * 64;
    const int tid = threadIdx.x;
    const float* src = x + (size_t)b * IN_DIM * NT;
    for (int idx = tid; idx < 4096; idx += 256) {
        const int kk = idx >> 6, tt = idx & 63;
        t[kk][tt] = src[(size_t)(k0 + kk) * NT + t0 + tt];
    }
    __syncthreads();
    for (int idx = tid; idx < 4096; idx += 256) {
        const int tt = idx >> 6, kk = idx & 63;
        Axt[((size_t)b * NT + t0 + tt) * IN_DIM + k0 + kk] =
            __float2bfloat16(t[kk][tt]);
    }
}

__global__ void fill_ihb(const float* __restrict__ init_h,
                         __hip_bfloat16* __restrict__ ihb)
{
    const int l = threadIdx.x;
    ihb[l] = __float2bfloat16(init_h[l]);
}

// ---------------------------------------------------------------------------
// Kernel 1 (MFMA 16x16x32): P = Axt @ WfT^T (64 rows x 512 cols per block),
// p = cos(P+bf), LN over cols, write zbuf [M][512] bf16.
// ---------------------------------------------------------------------------
__global__ __launch_bounds__(512, 2) void k1_mfma_fourier_ln(
    const __hip_bfloat16* __restrict__ Axt,   // [M_TOT][256]
    const __hip_bfloat16* __restrict__ WfT,   // [512][256]
    const float* __restrict__ bf, const float* __restrict__ gamma,
    const float* __restrict__ beta,
    __hip_bfloat16* __restrict__ zb)
{
    constexpr int ABYTES = 64 * 128;          // 8 KB
    constexpr int BBYTES = 512 * 128;         // 64 KB
    constexpr int NBUFB  = ABYTES + BBYTES;
    __shared__ __align__(16) char lds[2 * NBUFB];     // 144 KB
    __shared__ float pS[64][8], pQ[64][8];
    __shared__ float mS[64], rS[64];

    const int tid  = threadIdx.x;
    const int wave = tid >> 6, lane = tid & 63;
    const int m0 = blockIdx.x * 64;

    f32x4 acc[4][4];
#pragma unroll
    for (int mi = 0; mi < 4; mi++)
#pragma unroll
        for (int ni = 0; ni < 4; ni++) acc[mi][ni] = f32x4{0.f, 0.f, 0.f, 0.f};

    const int rowq = tid >> 3;
    const int sswz = ((tid & 7) ^ (rowq & 7)) << 4;
    const char* Ab = (const char*)Axt;
    const char* Bb = (const char*)WfT;

    auto stage = [&](int buf, int kt) {
        const size_t kb = (size_t)kt * 128;
        char* base = lds + buf * NBUFB;
        async_copy16(base + tid * 16,
                     Ab + (size_t)(m0 + rowq) * 512 + kb + sswz);
#pragma unroll
        for (int j = 0; j < 8; j++) {
            const int row = j * 64 + rowq;
            async_copy16(base + ABYTES + (j * 512 + tid) * 16,
                         Bb + (size_t)row * 512 + kb + sswz);
        }
    };

    const int l15 = lane & 15, lq = lane >> 4, l7 = lane & 7;
    int kxB[2];
#pragma unroll
    for (int ks = 0; ks < 2; ks++) kxB[ks] = ((ks * 4 + lq) ^ l7) << 4;

    stage(0, 0);
    int cur = 0;
#pragma unroll 1
    for (int kt = 0; kt < 4; kt++) {
        __syncthreads();
        if (kt + 1 < 4) stage(cur ^ 1, kt + 1);
        const char* sA = lds + cur * NBUFB;
        const char* sB = sA + ABYTES;
#pragma unroll
        for (int ks = 0; ks < 2; ks++) {
            const int kx = kxB[ks];
            short8 a[4], b[4];
#pragma unroll
            for (int mi = 0; mi < 4; mi++)
                a[mi] = *(const short8*)(sA + (size_t)(mi * 16 + l15) * 128 + kx);
#pragma unroll
            for (int ni = 0; ni < 4; ni++)
                b[ni] = *(const short8*)(sB +
                    (size_t)(wave * 64 + ni * 16 + l15) * 128 + kx);
#pragma unroll
            for (int ni = 0; ni < 4; ni++)
#pragma unroll
                for (int mi = 0; mi < 4; mi++)
                    acc[mi][ni] = __builtin_amdgcn_mfma_f32_16x16x32_bf16(
                        a[mi], b[ni], acc[mi][ni], 0, 0, 0);
        }
        cur ^= 1;
    }

    int cg[4]; float bfc[4];
#pragma unroll
    for (int ni = 0; ni < 4; ni++) {
        cg[ni] = wave * 64 + ni * 16 + l15;
        bfc[ni] = bf[cg[ni]];
    }

#pragma unroll
    for (int mi = 0; mi < 4; mi++) {
#pragma unroll
        for (int r = 0; r < 4; r++) {
            float s = 0.f, q = 0.f;
#pragma unroll
            for (int ni = 0; ni < 4; ni++) {
                const float p = __cosf(acc[mi][ni][r] + bfc[ni]);
                s += p; q += p * p;
            }
#pragma unroll
            for (int off = 8; off >= 1; off >>= 1) {
                s += __shfl_xor(s, off);
                q += __shfl_xor(q, off);
            }
            if (l15 == 0) {
                const int row = mi * 16 + lq * 4 + r;
                pS[row][wave] = s;
                pQ[row][wave] = q;
            }
        }
    }
    __syncthreads();
    if (tid < 64) {
        float a = 0.f, qq = 0.f;
#pragma unroll
        for (int w = 0; w < 8; w++) { a += pS[tid][w]; qq += pQ[tid][w]; }
        const float mu = a * (1.0f / NL);
        const float var = qq * (1.0f / NL) - mu * mu;
        mS[tid] = mu;
        rS[tid] = rsqrtf(var + LN_EPS);
    }
    __syncthreads();

    float gm[4], bt[4];
#pragma unroll
    for (int ni = 0; ni < 4; ni++) { gm[ni] = gamma[cg[ni]]; bt[ni] = beta[cg[ni]]; }

#pragma unroll
    for (int mi = 0; mi < 4; mi++) {
#pragma unroll
        for (int r = 0; r < 4; r++) {
            const int row = mi * 16 + lq * 4 + r;
            const int m = m0 + row;
            const float mu = mS[row], rs = rS[row];
#pragma unroll
            for (int ni = 0; ni < 4; ni++) {
                const float p = __cosf(acc[mi][ni][r] + bfc[ni]);
                const float z = gm[ni] * (p - mu) * rs + bt[ni];
                zb[(size_t)m * 512 + cg[ni]] = __float2bfloat16(z);
            }
        }
    }
}

// ---------------------------------------------------------------------------
// Weight transpose+convert / conn convert
// ---------------------------------------------------------------------------
__global__ __launch_bounds__(256) void wconv_transpose(
    const float* __restrict__ src, __hip_bfloat16* __restrict__ dst,
    int K, int N, int lddst, int k_off)
{
    __shared__ float t[64][65];
    const int ntn = N >> 6;
    const int k0 = (blockIdx.x / ntn) << 6;
    const int n0 = (blockIdx.x % ntn) << 6;
    const int tid = threadIdx.x;
    for (int idx = tid; idx < 4096; idx += 256) {
        const int kk = idx >> 6, nn = idx & 63;
        t[kk][nn] = src[(size_t)(k0 + kk) * N + n0 + nn];
    }
    __syncthreads();
    for (int idx = tid; idx < 4096; idx += 256) {
        const int nn = idx >> 6, kk = idx & 63;
        dst[(size_t)(n0 + nn) * lddst + k_off + k0 + kk] = __float2bfloat16(t[kk][nn]);
    }
}

__global__ __launch_bounds__(256) void conv_bf16_vec(
    const float* __restrict__ src, __hip_bfloat16* __restrict__ dst, int n)
{
    const int e = (blockIdx.x * 256 + threadIdx.x) * 4;
    if (e < n) {
        const float4 v = *(const float4*)(src + e);
        dst[e + 0] = __float2bfloat16(v.x);
        dst[e + 1] = __float2bfloat16(v.y);
        dst[e + 2] = __float2bfloat16(v.z);
        dst[e + 3] = __float2bfloat16(v.w);
    }
}

// ---------------------------------------------------------------------------
// m97-style MFMA GEMM: 128x128 tile, BK=64, 4 waves (2x2), 16x16x32 frags,
// double-buffered stage-ahead, 64 KB LDS -> 2 blocks/CU. XCD-swizzled grid.
// EPI 0: ub[m][n] = bf16(acc + bc[n])                     (u-GEMM, KTOT=256)
// EPI 1: merged gates, B rows 0..511 = [Wi;Ri], 512..1023 = [Wg;Rg]:
//        n<512 : iu = sigmoid(acc+bi)*u  -> ub (u read from ub)
//        n>=512: f  = sigmoid(acc+bg)    -> fb
//        A is stitched: K<512 from zbuf[m], K>=512 from zbuf[m-1] / ihb(t=0)
// ---------------------------------------------------------------------------
template<int KTOT, int EPI>
__global__ __launch_bounds__(256, 2) void gemm128(
    const __hip_bfloat16* __restrict__ A,
    const __hip_bfloat16* __restrict__ B,
    const __hip_bfloat16* __restrict__ ihb,
    const float* __restrict__ bi, const float* __restrict__ bg,
    const float* __restrict__ bc,
    __hip_bfloat16* __restrict__ fb, __hip_bfloat16* __restrict__ ub)
{
    constexpr int NTN = (EPI == 1) ? 8 : 4;   // N-tiles
    constexpr int TB  = KTOT / 64;            // K-steps
    __shared__ __align__(16) char lds[2][32768];   // [buf][A 16K | B 16K]

    const int tid  = threadIdx.x;
    const int wave = tid >> 6, lane = tid & 63;
    const int wm = wave >> 1, wn = wave & 1;
    // XCD swizzle, m-major within XCD (A-panel L2 reuse)
    constexpr int CPX = 128 * NTN / 8;
    const int d = blockIdx.x;
    const int L = (d & 7) * CPX + (d >> 3);
    const int m0 = (L / NTN) << 7;
    const int n0 = (L % NTN) << 7;

    f32x4 acc[4][4];
#pragma unroll
    for (int mi = 0; mi < 4; mi++)
#pragma unroll
        for (int ni = 0; ni < 4; ni++) acc[mi][ni] = f32x4{0.f, 0.f, 0.f, 0.f};

    auto stage = [&](int buf, int kt) {
        char* base = &lds[buf][0];
#pragma unroll
        for (int j = 0; j < 4; j++) {
            const int i = j * 256 + tid;
            const int r = i >> 3;                       // tile row 0..127
            const int sl = (i & 7) ^ (r & 7);           // logical 16B slot
            const int ke = kt * 64 + sl * 8;            // K element offset
            const __hip_bfloat16* srcA;
            if constexpr (EPI == 1) {
                const int m = m0 + r;
                if (ke < 512) {
                    srcA = A + (size_t)m * 512 + ke;
                } else {
                    const int k2 = ke - 512;
                    srcA = ((m & (NT - 1)) == 0) ? (ihb + k2)
                                                 : (A + (size_t)(m - 1) * 512 + k2);
                }
            } else {
                srcA = A + (size_t)(m0 + r) * KTOT + ke;
            }
            async_copy16(base + i * 16, srcA);
            async_copy16(base + 16384 + i * 16,
                         B + (size_t)(n0 + r) * KTOT + ke);
        }
    };

    const int l15 = lane & 15, lq = lane >> 4, l7 = lane & 7;
    int kx[2];
#pragma unroll
    for (int ks = 0; ks < 2; ks++) kx[ks] = ((ks * 4 + lq) ^ l7) << 4;

    stage(0, 0);
    int cur = 0;
#pragma unroll 1
    for (int kt = 0; kt < TB; kt++) {
        __syncthreads();                 // buf[cur] staged; buf[cur^1] free
        if (kt + 1 < TB) stage(cur ^ 1, kt + 1);
        const char* sA = &lds[cur][0];
        const char* sB = &lds[cur][16384];
#pragma unroll
        for (int ks = 0; ks < 2; ks++) {
            short8 a[4], b[4];
#pragma unroll
            for (int mi = 0; mi < 4; mi++)
                a[mi] = *(const short8*)(sA +
                    (size_t)(wm * 64 + mi * 16 + l15) * 128 + kx[ks]);
#pragma unroll
            for (int ni = 0; ni < 4; ni++)
                b[ni] = *(const short8*)(sB +
                    (size_t)(wn * 64 + ni * 16 + l15) * 128 + kx[ks]);
#pragma unroll
            for (int ni = 0; ni < 4; ni++)
#pragma unroll
                for (int mi = 0; mi < 4; mi++)
                    acc[mi][ni] = __builtin_amdgcn_mfma_f32_16x16x32_bf16(
                        a[mi], b[ni], acc[mi][ni], 0, 0, 0);
        }
        cur ^= 1;
    }

    // epilogue: C/D col = lane&15, row = mi*16 + lq*4 + r
#pragma unroll
    for (int ni = 0; ni < 4; ni++) {
        const int gcol = n0 + wn * 64 + ni * 16 + l15;
        if constexpr (EPI == 0) {
            const float bcl = bc[gcol];
#pragma unroll
            for (int mi = 0; mi < 4; mi++)
#pragma unroll
                for (int r = 0; r < 4; r++) {
                    const int m = m0 + wm * 64 + mi * 16 + lq * 4 + r;
                    ub[(size_t)m * 512 + gcol] =
                        __float2bfloat16(acc[mi][ni][r] + bcl);
                }
        } else {
            if (gcol < 512) {
                const float bil = bi[gcol];
#pragma unroll
                for (int mi = 0; mi < 4; mi++)
#pragma unroll
                    for (int r = 0; r < 4; r++) {
                        const int m = m0 + wm * 64 + mi * 16 + lq * 4 + r;
                        const size_t idx = (size_t)m * 512 + gcol;
                        const float iv =
                            1.f / (1.f + __expf(-(acc[mi][ni][r] + bil)));
                        const float uv = __bfloat162float(ub[idx]);
                        ub[idx] = __float2bfloat16(iv * uv);
                    }
            } else {
                const int l2 = gcol - 512;
                const float bgl = bg[l2];
#pragma unroll
                for (int mi = 0; mi < 4; mi++)
#pragma unroll
                    for (int r = 0; r < 4; r++) {
                        const int m = m0 + wm * 64 + mi * 16 + lq * 4 + r;
                        const float fv =
                            1.f / (1.f + __expf(-(acc[mi][ni][r] + bgl)));
                        fb[(size_t)m * 512 + l2] = __float2bfloat16(fv);
                    }
            }
        }
    }
}

// ---------------------------------------------------------------------------
// Kernel 3: sequential scan; h = sin(z)*c; out[b,l,t].
// ---------------------------------------------------------------------------
__global__ __launch_bounds__(64) void k3_scan(
    const __hip_bfloat16* __restrict__ zb,
    const __hip_bfloat16* __restrict__ fb,
    const __hip_bfloat16* __restrict__ ub,
    const float* __restrict__ init_c, float* __restrict__ out)
{
    const int b = blockIdx.x >> 3;
    const int l = ((blockIdx.x & 7) << 6) + threadIdx.x;
    float c = init_c[l];

    const __hip_bfloat16* zp = zb + (size_t)b * NT * 512 + l;
    const __hip_bfloat16* fp = fb + (size_t)b * NT * NL + l;
    const __hip_bfloat16* ip = ub + (size_t)b * NT * NL + l;
    float* op = out + ((size_t)b * NL + l) * NT;

    for (int t0 = 0; t0 < NT; t0 += 16) {
        float fv[16], iv[16], zv[16];
#pragma unroll
        for (int j = 0; j < 16; j++) {
            fv[j] = __bfloat162float(fp[(size_t)(t0 + j) * NL]);
            iv[j] = __bfloat162float(ip[(size_t)(t0 + j) * NL]);
            zv[j] = __bfloat162float(zp[(size_t)(t0 + j) * 512]);
        }
        float h[16];
#pragma unroll
        for (int j = 0; j < 16; j++) {
            c = fv[j] * c + iv[j];
            h[j] = __sinf(zv[j]) * c;
        }
        float4* o4 = (float4*)(op + t0);
        o4[0] = make_float4(h[0],  h[1],  h[2],  h[3]);
        o4[1] = make_float4(h[4],  h[5],  h[6],  h[7]);
        o4[2] = make_float4(h[8],  h[9],  h[10], h[11]);
        o4[3] = make_float4(h[12], h[13], h[14], h[15]);
    }
}

// ---------------------------------------------------------------------------
extern "C" void kernel_launch(void* const* d_in, const int* in_sizes, int n_in,
                              void* d_out, int out_size, void* d_ws, size_t ws_size,
                              hipStream_t stream)
{
    const float* x      = (const float*)d_in[0];
    const float* conn   = (const float*)d_in[1];
    const float* Wf     = (const float*)d_in[2];
    const float* bfv    = (const float*)d_in[3];
    const float* gamma  = (const float*)d_in[4];
    const float* beta   = (const float*)d_in[5];
    const float* Wi     = (const float*)d_in[6];
    const float* Ri     = (const float*)d_in[7];
    const float* bi     = (const float*)d_in[8];
    const float* Wg     = (const float*)d_in[9];
    const float* Rg     = (const float*)d_in[10];
    const float* bg     = (const float*)d_in[11];
    const float* Wc     = (const float*)d_in[12];
    const float* bc     = (const float*)d_in[13];
    const float* init_h = (const float*)d_in[14];
    const float* init_c = (const float*)d_in[15];

    char* w = (char*)d_ws;
    __hip_bfloat16* zbuf = (__hip_bfloat16*)w;  w += (size_t)M_TOT * 512 * 2;
    __hip_bfloat16* cbuf = (__hip_bfloat16*)w;  w += (size_t)M_TOT * NCONN * 2;
    __hip_bfloat16* fbuf = (__hip_bfloat16*)w;  w += (size_t)M_TOT * NL * 2;
    __hip_bfloat16* ubuf = (__hip_bfloat16*)w;  w += (size_t)M_TOT * NL * 2;
    __hip_bfloat16* xbuf = (__hip_bfloat16*)w;  w += (size_t)M_TOT * IN_DIM * 2;
    __hip_bfloat16* WfT  = (__hip_bfloat16*)w;  w += (size_t)NL * IN_DIM * 2;
    __hip_bfloat16* Btig = (__hip_bfloat16*)w;  w += (size_t)1024 * 1024 * 2;
    __hip_bfloat16* Btc  = (__hip_bfloat16*)w;  w += (size_t)NL * NCONN * 2;
    __hip_bfloat16* ihb  = (__hip_bfloat16*)w;  w += 512 * 2;

    // prep: Btig rows 0..511 = [Wi;Ri]^T, rows 512..1023 = [Wg;Rg]^T
    wconv_transpose<<<32, 256, 0, stream>>>(Wf, WfT, 256, 512, 256, 0);
    wconv_transpose<<<64, 256, 0, stream>>>(Wi, Btig, 512, 512, 1024, 0);
    wconv_transpose<<<64, 256, 0, stream>>>(Ri, Btig, 512, 512, 1024, 512);
    wconv_transpose<<<64, 256, 0, stream>>>(Wg, Btig + (size_t)512 * 1024, 512, 512, 1024, 0);
    wconv_transpose<<<64, 256, 0, stream>>>(Rg, Btig + (size_t)512 * 1024, 512, 512, 1024, 512);
    wconv_transpose<<<32, 256, 0, stream>>>(Wc, Btc, 256, 512, 256, 0);
    conv_bf16_vec<<<(M_TOT * NCONN / 4 + 255) / 256, 256, 0, stream>>>(
        conn, cbuf, M_TOT * NCONN);
    xprep_transpose<<<NB * 32, 256, 0, stream>>>(x, xbuf);
    fill_ihb<<<1, 512, 0, stream>>>(init_h, ihb);

    // z = LN(cos(x^T Wf + bf)) -> zbuf [M][512]
    k1_mfma_fourier_ln<<<M_TOT / 64, 512, 0, stream>>>(
        xbuf, WfT, bfv, gamma, beta, zbuf);

    // u = conn @ Wc + bc -> ubuf
    gemm128<NCONN, 0><<<M_TOT / 128 * 4, 256, 0, stream>>>(
        cbuf, Btc, nullptr, nullptr, nullptr, bc, nullptr, ubuf);

    // merged gates: N=1024 over Btig; stitched A = [z | z_prev]
    gemm128<1024, 1><<<M_TOT / 128 * 8, 256, 0, stream>>>(
        zbuf, Btig, ihb, bi, bg, nullptr, fbuf, ubuf);

    k3_scan<<<NB * 8, 64, 0, stream>>>(zbuf, fbuf, ubuf, init_c, (float*)d_out);
}